// Round 16
// baseline (217.917 us; speedup 1.0000x reference)
//
#include <hip/hip_runtime.h>
#include <hip/hip_bf16.h>
#include <math.h>

typedef short bf16x8 __attribute__((ext_vector_type(8)));
typedef float f32x4 __attribute__((ext_vector_type(4)));

union BU8 { uint4 u; __hip_bfloat16 h[8]; ushort s[8]; };

#define LOG2E 1.44269504f
#define LN2   0.69314718f
#define NIV3  9            // spline intervals
#define NND3  12           // nodes = NIV3 + 3  (192 tasks = 3 full waves)

// ---------- small helpers ----------
__device__ __forceinline__ float3 f3sub(float3 a, float3 b){ return make_float3(a.x-b.x, a.y-b.y, a.z-b.z); }
__device__ __forceinline__ float3 f3nrm(float3 v){
  float n = sqrtf(v.x*v.x + v.y*v.y + v.z*v.z);
  float inv = 1.0f / fmaxf(n, 1e-8f);
  return make_float3(v.x*inv, v.y*inv, v.z*inv);
}
__device__ __forceinline__ float3 f3cross(float3 a, float3 b){
  return make_float3(a.y*b.z - a.z*b.y, a.z*b.x - a.x*b.z, a.x*b.y - a.y*b.x);
}
__device__ __forceinline__ float silu_f(float x){
  float ex = __expf(-x);
  return x * __builtin_amdgcn_rcpf(1.0f + ex);
}
__device__ __forceinline__ uint packbf2(float a, float b){
  ushort ua = __bfloat16_as_ushort(__float2bfloat16(a));
  ushort ub = __bfloat16_as_ushort(__float2bfloat16(b));
  return (uint)ua | ((uint)ub << 16);
}

// ---------- kernel 1: per-edge frame (inline) + diff + proj ----------
__global__ void edgepre_kernel(const float* __restrict__ posl, const float* __restrict__ posr,
    const int* __restrict__ el, const int* __restrict__ er,
    float* __restrict__ ediff, float* __restrict__ proj, int E, int Nr){
  int e = blockIdx.x*blockDim.x + threadIdx.x;
  if (e >= E) return;
  int a = el[e], r = er[e];
  float3 pa = make_float3(posl[3*a+0], posl[3*a+1], posl[3*a+2]);
  float3 pr = make_float3(posr[3*r+0], posr[3*r+1], posr[3*r+2]);
  float3 ed = f3nrm(f3sub(pa,pr));

  int k = r - 1;
  if (k < 0) k = 0;
  int kmax = Nr - 3;
  if (k > kmax) k = kmax;
  float3 p0 = make_float3(posr[3*k+0], posr[3*k+1], posr[3*k+2]);
  float3 p1 = make_float3(posr[3*k+3], posr[3*k+4], posr[3*k+5]);
  float3 p2 = make_float3(posr[3*k+6], posr[3*k+7], posr[3*k+8]);
  float3 u0 = f3nrm(f3sub(p1,p0));
  float3 u1 = f3nrm(f3sub(p2,p1));
  float3 dif = f3nrm(f3sub(u0,u1));
  float3 cr  = f3nrm(f3cross(u0,u1));
  float3 vt  = f3nrm(f3cross(dif,cr));

  float px = ed.x*dif.x + ed.y*cr.x + ed.z*vt.x;
  float py = ed.x*dif.y + ed.y*cr.y + ed.z*vt.y;
  float pz = ed.x*dif.z + ed.y*cr.z + ed.z*vt.z;
  ediff[3*e+0]=ed.x; ediff[3*e+1]=ed.y; ediff[3*e+2]=ed.z;
  proj[3*e+0]=px; proj[3*e+1]=py; proj[3*e+2]=pz;
}

// ---------- kernel P: weight transpose+convert + exp2-folded consts ----------
__global__ void prep_kernel(const float* __restrict__ Win1, const float* __restrict__ Win2,
                            __hip_bfloat16* __restrict__ W1t, __hip_bfloat16* __restrict__ W2t,
                            const float* __restrict__ bs1a, const float* __restrict__ Ws1b,
                            const float* __restrict__ bs2a, const float* __restrict__ Ws2b,
                            float* __restrict__ bneg, float* __restrict__ wln){
  int idx = blockIdx.x*blockDim.x + threadIdx.x;
  if (idx < 32768){
    int l = idx >> 14, rem = idx & 16383, n = rem >> 7, k = rem & 127;
    W1t[idx] = __float2bfloat16(Win1[(l<<14) + (k<<7) + n]);
  } else if (idx < 65536){
    int i2 = idx - 32768;
    int l = i2 >> 14, rem = i2 & 16383, n = rem >> 7, k = rem & 127;
    W2t[i2] = __float2bfloat16(Win2[(l<<14) + (k<<7) + n]);
  }
  if (blockIdx.x == 0 && threadIdx.x < 128){
    int t = threadIdx.x;
    int l = t >> 6, br = (t >> 5) & 1, q = t & 31;
    const float* ba = br ? bs2a : bs1a;
    const float* Wb = br ? Ws2b : Ws1b;
    bneg[t] = -ba[l*32 + q] * LOG2E;
    wln[t]  = -Wb[l*32 + q] * LN2;
  }
}

// ---------- kernel 3a: MFMA pre-GEMM, B in regs, both layers (grid.y = layer) ----------
__global__ __launch_bounds__(256) void pre_gemm_mfma(
    const float* __restrict__ lig, const float* __restrict__ res,
    const __hip_bfloat16* __restrict__ W1t,
    __hip_bfloat16* __restrict__ ligLb, __hip_bfloat16* __restrict__ resLb,
    int nBlkLig, int Nl, int Nr)
{
  __shared__ __hip_bfloat16 sA[64][136];
  int b = blockIdx.x;
  int layer = blockIdx.y;
  const __hip_bfloat16* Wt = W1t + (size_t)layer*16384;
  const float* X; __hip_bfloat16* O; int row0, rows;
  if (b < nBlkLig){ X = lig; O = ligLb + (size_t)layer*Nl*128; row0 = b*64;           rows = Nl; }
  else            { X = res; O = resLb + (size_t)layer*Nr*128; row0 = (b-nBlkLig)*64; rows = Nr; }
  int tid = threadIdx.x;
  int w = tid >> 6, l = tid & 63;
  int lrow = l & 15, lko = (l >> 4) * 8;

  // preload B fragments (block-invariant) into regs
  bf16x8 breg[4][2];
  #pragma unroll
  for (int kc4 = 0; kc4 < 4; ++kc4){
    #pragma unroll
    for (int nt = 0; nt < 2; ++nt)
      breg[kc4][nt] = *(const bf16x8*)((const ushort*)Wt + (w*32+nt*16+lrow)*128 + kc4*32 + lko);
  }

  {
    int r = tid >> 2, p = tid & 3, cb = p*32;
    int row = row0 + r; if (row >= rows) row = rows - 1;
    const float* src = X + (size_t)row*128 + cb;
    ushort* dst = (ushort*)&sA[r][0] + cb;
    #pragma unroll
    for (int i = 0; i < 32; i += 8){
      float4 v0 = *(const float4*)(src + i);
      float4 v1 = *(const float4*)(src + i + 4);
      BU8 o;
      o.h[0]=__float2bfloat16(v0.x); o.h[1]=__float2bfloat16(v0.y);
      o.h[2]=__float2bfloat16(v0.z); o.h[3]=__float2bfloat16(v0.w);
      o.h[4]=__float2bfloat16(v1.x); o.h[5]=__float2bfloat16(v1.y);
      o.h[6]=__float2bfloat16(v1.z); o.h[7]=__float2bfloat16(v1.w);
      *(uint4*)(dst + i) = o.u;
    }
  }
  __syncthreads();

  f32x4 acc[4][2];
  for (int mt=0; mt<4; ++mt)
    for (int nt=0; nt<2; ++nt)
      acc[mt][nt] = (f32x4){0.f,0.f,0.f,0.f};

  #pragma unroll
  for (int kc4 = 0; kc4 < 4; ++kc4){
    bf16x8 af[4];
    #pragma unroll
    for (int mt=0; mt<4; ++mt)
      af[mt] = *(const bf16x8*)((const ushort*)&sA[0][0] + (mt*16+lrow)*136 + kc4*32 + lko);
    #pragma unroll
    for (int mt=0; mt<4; ++mt){
      #pragma unroll
      for (int nt=0; nt<2; ++nt)
        acc[mt][nt] = __builtin_amdgcn_mfma_f32_16x16x32_bf16(af[mt], breg[kc4][nt], acc[mt][nt], 0, 0, 0);
    }
  }

  int orow = (l >> 4) * 4;
  #pragma unroll
  for (int mt=0; mt<4; ++mt){
    #pragma unroll
    for (int nt=0; nt<2; ++nt){
      int n = w*32 + nt*16 + (l & 15);
      #pragma unroll
      for (int j=0; j<4; ++j){
        int row = row0 + mt*16 + orow + j;
        if (row < rows) O[(size_t)row*128 + n] = __float2bfloat16(acc[mt][nt][j]);
      }
    }
  }
}

// ---------- kernel 3b: h-GEMM, B in regs, both layers (grid.y = layer) ----------
__global__ __launch_bounds__(256) void h_gemm2_mfma(
    const __hip_bfloat16* __restrict__ ligLbB, const __hip_bfloat16* __restrict__ resLbB,
    const int* __restrict__ el, const int* __restrict__ er,
    const float* __restrict__ b1B, const __hip_bfloat16* __restrict__ W2tB,
    const float* __restrict__ b2B,
    __hip_bfloat16* __restrict__ houtB, int E, int Nl, int Nr)
{
  __shared__ __hip_bfloat16 sA[64][136];
  int tid = threadIdx.x;
  int e0 = blockIdx.x * 64;
  int layer = blockIdx.y;
  const __hip_bfloat16* ligLb = ligLbB + (size_t)layer*Nl*128;
  const __hip_bfloat16* resLb = resLbB + (size_t)layer*Nr*128;
  const float* b1 = b1B + layer*128;
  const __hip_bfloat16* W2t = W2tB + (size_t)layer*16384;
  const float* b2 = b2B + layer*128;
  __hip_bfloat16* hout = houtB + (size_t)layer*E*128;

  int w = tid >> 6, l = tid & 63;
  int lrow = l & 15, lko = (l >> 4) * 8;

  // preload B fragments (block-invariant) into regs
  bf16x8 breg[4][2];
  #pragma unroll
  for (int kc4 = 0; kc4 < 4; ++kc4){
    #pragma unroll
    for (int nt = 0; nt < 2; ++nt)
      breg[kc4][nt] = *(const bf16x8*)((const ushort*)W2t + (w*32+nt*16+lrow)*128 + kc4*32 + lko);
  }

  {
    int r = tid >> 2, p = tid & 3, cb = p*32;
    int e = e0 + r; if (e >= E) e = E - 1;
    const ushort* la = (const ushort*)ligLb + (size_t)el[e]*128 + cb;
    const ushort* ra = (const ushort*)resLb + (size_t)er[e]*128 + cb;
    ushort* dst = (ushort*)&sA[r][0] + cb;
    #pragma unroll
    for (int i = 0; i < 32; i += 8){
      BU8 A, B, O;
      A.u = *(const uint4*)(la + i);
      B.u = *(const uint4*)(ra + i);
      float4 bb0 = *(const float4*)(b1 + cb + i);
      float4 bbx = *(const float4*)(b1 + cb + i + 4);
      float bbs[8] = {bb0.x,bb0.y,bb0.z,bb0.w,bbx.x,bbx.y,bbx.z,bbx.w};
      #pragma unroll
      for (int j=0; j<8; ++j){
        float x = __bfloat162float(A.h[j]) + __bfloat162float(B.h[j]) + bbs[j];
        O.h[j] = __float2bfloat16(silu_f(x));
      }
      *(uint4*)(dst + i) = O.u;
    }
  }
  __syncthreads();

  f32x4 acc[4][2];
  for (int mt=0; mt<4; ++mt)
    for (int nt=0; nt<2; ++nt)
      acc[mt][nt] = (f32x4){0.f,0.f,0.f,0.f};

  #pragma unroll
  for (int kc4 = 0; kc4 < 4; ++kc4){
    bf16x8 af[4];
    #pragma unroll
    for (int mt=0; mt<4; ++mt)
      af[mt] = *(const bf16x8*)((const ushort*)&sA[0][0] + (mt*16+lrow)*136 + kc4*32 + lko);
    #pragma unroll
    for (int mt=0; mt<4; ++mt){
      #pragma unroll
      for (int nt=0; nt<2; ++nt)
        acc[mt][nt] = __builtin_amdgcn_mfma_f32_16x16x32_bf16(af[mt], breg[kc4][nt], acc[mt][nt], 0, 0, 0);
    }
  }

  int orow = (l >> 4) * 4;
  #pragma unroll
  for (int mt=0; mt<4; ++mt){
    #pragma unroll
    for (int nt=0; nt<2; ++nt){
      int n = w*32 + nt*16 + (l & 15);
      float bb = b2[n];
      #pragma unroll
      for (int j=0; j<4; ++j){
        int e = e0 + mt*16 + orow + j;
        if (e < E) hout[(size_t)e*128 + n] = __float2bfloat16(acc[mt][nt][j] + bb);
      }
    }
  }
}

// ---------- kernel 4a: per-edge Catmull-Rom spline + inline eval ----------
#define SEPB 16
__global__ __launch_bounds__(256) void spline_kernel(
    __hip_bfloat16* __restrict__ hbufB, const float* __restrict__ proj,
    const float* __restrict__ Ws1a, const float* __restrict__ Ws2a,
    const float* __restrict__ bs1b, const float* __restrict__ bs2b,
    const float* __restrict__ bnegB, const float* __restrict__ wlnB,
    __hip_bfloat16* __restrict__ w02B, int E)
{
  int layer = blockIdx.y;
  const float* Wa1 = Ws1a + layer*96;
  const float* Wa2 = Ws2a + layer*96;
  const float* bneg = bnegB + layer*64;
  const float* wln  = wlnB  + layer*64;
  float bb1v = bs1b[layer], bb2v = bs2b[layer];
  __hip_bfloat16* hb  = hbufB + (size_t)layer*E*128;
  __hip_bfloat16* w2o = w02B  + (size_t)layer*E*128;

  __shared__ float sA[2][SEPB][36];
  __shared__ float sNF[SEPB][2][NND3];
  __shared__ ushort sH[SEPB][128];
  __shared__ uint  sCo[SEPB][4*NIV3];
  __shared__ float sMin[SEPB], sMax[SEPB];
  __shared__ float sH0[SEPB], sDv[SEPB], sInvD[SEPB], sP0[SEPB];

  int tid = threadIdx.x;
  int eb0 = blockIdx.x * SEPB;

  // P1: stage h rows + per-edge min/max (16 threads/edge)
  {
    int et = tid >> 4, sg = tid & 15;
    int e = eb0 + et; if (e >= E) e = E-1;
    uint4 raw = *(const uint4*)((const ushort*)hb + (size_t)e*128 + sg*8);
    *(uint4*)&sH[et][sg*8] = raw;
    uint us[4] = {raw.x, raw.y, raw.z, raw.w};
    float mn = 1e30f, mx = -1e30f;
    #pragma unroll
    for (int i=0;i<4;i++){
      float lo = __uint_as_float(us[i]<<16);
      float hi = __uint_as_float(us[i]&0xFFFF0000u);
      mn = fminf(mn, fminf(lo,hi)); mx = fmaxf(mx, fmaxf(lo,hi));
    }
    #pragma unroll
    for (int o=8;o>0;o>>=1){ mn=fminf(mn,__shfl_xor(mn,o)); mx=fmaxf(mx,__shfl_xor(mx,o)); }
    if (sg==0){ sMin[et]=mn; sMax[et]=mx; }
  }
  __syncthreads();

  // P1b: per-edge A'_q (folded -log2e) + scalars
  for (int t=tid; t<2*SEPB*32; t+=256){
    int et = t>>6, rem = t&63, br = rem>>5, q = rem&31;
    int e = eb0+et; if (e>=E) e=E-1;
    const float* Wa = br ? Wa2 : Wa1;
    float p0=proj[3*e], p1=proj[3*e+1], p2=proj[3*e+2];
    sA[br][et][q] = -(p0*Wa[q]+p1*Wa[32+q]+p2*Wa[64+q])*LOG2E;
  }
  if (tid < SEPB){
    int e = eb0+tid; if (e>=E) e=E-1;
    float range = fmaxf(sMax[tid]-sMin[tid], 1e-3f);
    sH0[tid]=sMin[tid]; sDv[tid]=range*(1.0f/NIV3); sInvD[tid]=(float)NIV3/range;
    sP0[tid]=proj[3*e];
  }
  __syncthreads();

  // P2: value-only node f at 12 nodes (192 tasks = 3 waves; wave 3 skips)
  if (tid < SEPB*NND3){
    int et = tid / NND3, nd = tid - et*NND3;
    float hn = fmaf((float)(nd-1), sDv[et], sH0[et]);
    const float* A0 = &sA[0][et][0];
    const float* A1 = &sA[1][et][0];
    float f0 = 0.f, f1 = 0.f;
    #pragma unroll
    for (int q = 0; q < 32; ++q){
      float x0 = fmaf(hn, A0[q], bneg[q]);
      float x1 = fmaf(hn, A1[q], bneg[32+q]);
      float e0 = __builtin_amdgcn_exp2f(x0);
      float e1 = __builtin_amdgcn_exp2f(x1);
      float d0 = 1.0f + e0, d1 = 1.0f + e1;
      float r  = __builtin_amdgcn_rcpf(d0*d1);
      f0 = fmaf(wln[q],    x0*(r*d1), f0);
      f1 = fmaf(wln[32+q], x1*(r*d0), f1);
    }
    sNF[et][0][nd] = f0;
    sNF[et][1][nd] = f1;
  }
  __syncthreads();

  // P2.5: Catmull-Rom coeffs (9 intervals x 2 br x 16 edges = 288 tasks)
  for (int t=tid; t<2*SEPB*NIV3; t+=256){
    int et = t/(2*NIV3), rem = t - et*(2*NIV3), br = rem/NIV3, i = rem - br*NIV3;
    const float* F = &sNF[et][br][0];
    float P0=F[i], P1=F[i+1], P2=F[i+2], P3=F[i+3];
    float bb = br ? bb2v : bb1v;
    float c0 = P1 + bb;
    float c1 = 0.5f*(P2 - P0);
    float c2 = P0 - 2.5f*P1 + 2.0f*P2 - 0.5f*P3;
    float c3 = 0.5f*(P3 - P0) + 1.5f*(P1 - P2);
    sCo[et][br*2*NIV3 + 2*i]     = packbf2(c0, c1);
    sCo[et][br*2*NIV3 + 2*i + 1] = packbf2(c2, c3);
  }
  __syncthreads();

  // P3: inline eval — 512 tasks (16 edges x 32 groups of 4 channels)
  for (int t=tid; t<512; t+=256){
    int et = t>>5, g = t&31;
    int e = eb0 + et;
    if (e < E){
      int d0 = g*4;
      ushort4 hv4 = *(const ushort4*)&sH[et][d0];
      float h0=sH0[et], invD=sInvD[et], p0=sP0[et];
      ushort hvs[4] = {hv4.x, hv4.y, hv4.z, hv4.w};
      ushort o1[4], o2[4];
      #pragma unroll
      for (int k=0;k<4;++k){
        float h = __uint_as_float(((uint)hvs[k])<<16);
        float u = (h - h0) * invD;
        int ii = (int)u; ii = ii < 0 ? 0 : (ii > NIV3-1 ? NIV3-1 : ii);
        float s = u - (float)ii;
        uint cA0 = sCo[et][2*ii],            cA1 = sCo[et][2*ii+1];
        uint cB0 = sCo[et][2*NIV3+2*ii],     cB1 = sCo[et][2*NIV3+2*ii+1];
        float c0 = __uint_as_float(cA0<<16), c1 = __uint_as_float(cA0&0xFFFF0000u);
        float c2 = __uint_as_float(cA1<<16), c3 = __uint_as_float(cA1&0xFFFF0000u);
        float v1 = fmaf(fmaf(fmaf(c3,s,c2),s,c1),s,c0);
        float e0f = __uint_as_float(cB0<<16), e1f = __uint_as_float(cB0&0xFFFF0000u);
        float e2f = __uint_as_float(cB1<<16), e3f = __uint_as_float(cB1&0xFFFF0000u);
        float v2 = fmaf(fmaf(fmaf(e3f,s,e2f),s,e1f),s,e0f);
        float hp = h * p0;
        o1[k] = __bfloat16_as_ushort(__float2bfloat16(v1 + hp));
        o2[k] = __bfloat16_as_ushort(__float2bfloat16(v2 + hp));
      }
      ushort4 O1 = {o1[0],o1[1],o1[2],o1[3]};
      ushort4 O2 = {o2[0],o2[1],o2[2],o2[3]};
      *(ushort4*)((ushort*)hb  + (size_t)e*128 + d0) = O1;   // w01 in-place
      *(ushort4*)((ushort*)w2o + (size_t)e*128 + d0) = O2;
    }
  }
}

// ---------- kernel 4b: per-atom streaming reduce, BOTH layers per block ----------
__global__ __launch_bounds__(128) void reduce_kernel(
    const __hip_bfloat16* __restrict__ w01B, const __hip_bfloat16* __restrict__ w02B,
    const float* __restrict__ ediff, const int* __restrict__ el,
    float* __restrict__ tvec, float* __restrict__ sumwb, int E, int Nl)
{
  __shared__ float sEd[64][3];
  int a = blockIdx.x;
  int d = threadIdx.x;
  const __hip_bfloat16* w01L0 = w01B;
  const __hip_bfloat16* w02L0 = w02B;
  const __hip_bfloat16* w01L1 = w01B + (size_t)E*128;
  const __hip_bfloat16* w02L1 = w02B + (size_t)E*128;

  int lo = 0, hi = E;
  while (lo < hi){ int m = (lo+hi)>>1; if (el[m] < a) lo = m+1; else hi = m; }
  int estart = lo;
  int lo2 = lo, hi2 = E;
  while (lo2 < hi2){ int m = (lo2+hi2)>>1; if (el[m] <= a) lo2 = m+1; else hi2 = m; }
  int eend = lo2;

  float s0=0.f, tx0=0.f, ty0=0.f, tz0=0.f;
  float s1=0.f, tx1=0.f, ty1=0.f, tz1=0.f;

  for (int ebase = estart; ebase < eend; ebase += 64){
    int n = min(64, eend - ebase);
    __syncthreads();
    for (int t = d; t < n*3; t += 128)
      ((float*)sEd)[t] = ediff[(size_t)ebase*3 + t];
    __syncthreads();

    #pragma unroll 4
    for (int ei = 0; ei < n; ++ei){
      size_t idx = (size_t)(ebase+ei)*128 + d;
      float a1 = __bfloat162float(w01L0[idx]);
      float b1 = __bfloat162float(w02L0[idx]);
      float a2 = __bfloat162float(w01L1[idx]);
      float b2 = __bfloat162float(w02L1[idx]);
      float ex = sEd[ei][0], ey = sEd[ei][1], ez = sEd[ei][2];
      s0 += a1;  s1 += a2;
      tx0 = fmaf(ex, b1, tx0);  tx1 = fmaf(ex, b2, tx1);
      ty0 = fmaf(ey, b1, ty0);  ty1 = fmaf(ey, b2, ty1);
      tz0 = fmaf(ez, b1, tz0);  tz1 = fmaf(ez, b2, tz1);
    }
  }

  size_t t0b = (size_t)a*384 + d;
  tvec[t0b      ] = tx0;
  tvec[t0b + 128] = ty0;
  tvec[t0b + 256] = tz0;
  size_t t1b = (size_t)Nl*384 + t0b;
  tvec[t1b      ] = tx1;
  tvec[t1b + 128] = ty1;
  tvec[t1b + 256] = tz1;
  sumwb[(size_t)a*128 + d] = s0;
  sumwb[(size_t)Nl*128 + (size_t)a*128 + d] = s1;
}

// ---------- kernel 5: combine (lv = t0*(1+sumw1)+t1) + head ----------
__global__ __launch_bounds__(128) void head_kernel(
    const float* __restrict__ tvec, const float* __restrict__ sumwb,
    const float* __restrict__ Wl1, const float* __restrict__ bl1,
    const float* __restrict__ Wl2, const float* __restrict__ bl2,
    const float* __restrict__ lvin, float* __restrict__ out, int Nl)
{
  int a = blockIdx.x, d = threadIdx.x;
  __shared__ float slv[3][128];
  __shared__ float sred[2][3];
  const float* t0 = tvec + (size_t)a*384;
  const float* t1 = tvec + (size_t)Nl*384 + (size_t)a*384;
  float m = 1.0f + sumwb[(size_t)Nl*128 + (size_t)a*128 + d];
  slv[0][d] = t0[d      ]*m + t1[d      ];
  slv[1][d] = t0[d + 128]*m + t1[d + 128];
  slv[2][d] = t0[d + 256]*m + t1[d + 256];
  __syncthreads();
  float b = bl1[d];
  float a0 = b, a1 = b, a2 = b;
  #pragma unroll 4
  for (int k = 0; k < 128; ++k) {
    float w = Wl1[k*128 + d];
    a0 = fmaf(slv[0][k], w, a0);
    a1 = fmaf(slv[1][k], w, a1);
    a2 = fmaf(slv[2][k], w, a2);
  }
  float wl2 = Wl2[d];
  float z0 = fmaxf(a0, 0.f)*wl2;
  float z1 = fmaxf(a1, 0.f)*wl2;
  float z2 = fmaxf(a2, 0.f)*wl2;
  #pragma unroll
  for (int off = 32; off > 0; off >>= 1) {
    z0 += __shfl_down(z0, off);
    z1 += __shfl_down(z1, off);
    z2 += __shfl_down(z2, off);
  }
  int wv = d >> 6;
  if ((d & 63) == 0) { sred[wv][0]=z0; sred[wv][1]=z1; sred[wv][2]=z2; }
  __syncthreads();
  if (d == 0) {
    float bb = bl2[0];
    out[a*3+0] = sred[0][0]+sred[1][0] + bb + lvin[a*3+0];
    out[a*3+1] = sred[0][1]+sred[1][1] + bb + lvin[a*3+1];
    out[a*3+2] = sred[0][2]+sred[1][2] + bb + lvin[a*3+2];
  }
}

// ---------- launcher ----------
extern "C" void kernel_launch(void* const* d_in, const int* in_sizes, int n_in,
                              void* d_out, int out_size, void* d_ws, size_t ws_size,
                              hipStream_t stream)
{
  const float* lig   = (const float*)d_in[0];
  const float* lvin  = (const float*)d_in[1];
  const float* posl  = (const float*)d_in[2];
  const float* res   = (const float*)d_in[3];
  const float* posr  = (const float*)d_in[4];
  const int*   el    = (const int*)d_in[7];
  const int*   er    = (const int*)d_in[8];
  const float* Win1  = (const float*)d_in[9];
  const float* bin1  = (const float*)d_in[10];
  const float* Win2  = (const float*)d_in[11];
  const float* bin2  = (const float*)d_in[12];
  const float* Ws1a  = (const float*)d_in[13];
  const float* bs1a  = (const float*)d_in[14];
  const float* Ws1b  = (const float*)d_in[15];
  const float* bs1b  = (const float*)d_in[16];
  const float* Ws2a  = (const float*)d_in[17];
  const float* bs2a  = (const float*)d_in[18];
  const float* Ws2b  = (const float*)d_in[19];
  const float* bs2b  = (const float*)d_in[20];
  const float* Wl1   = (const float*)d_in[21];
  const float* bl1   = (const float*)d_in[22];
  const float* Wl2   = (const float*)d_in[23];
  const float* bl2   = (const float*)d_in[24];

  int Nl = in_sizes[2] / 3;
  int Nr = in_sizes[4] / 3;
  int E  = in_sizes[7];

  char* wsb = (char*)d_ws;
  size_t off = 0;
  auto carve = [&](size_t bytes) -> char* {
    char* p = wsb + off;
    off += (bytes + 255) & ~(size_t)255;
    return p;
  };
  float* ediff  = (float*)carve((size_t)E*3*4);
  float* proj   = (float*)carve((size_t)E*3*4);
  __hip_bfloat16* hbuf2  = (__hip_bfloat16*)carve((size_t)2*E*128*2);  // h, then w01 in-place
  __hip_bfloat16* w02b   = (__hip_bfloat16*)carve((size_t)2*E*128*2);
  __hip_bfloat16* ligLb2 = (__hip_bfloat16*)carve((size_t)2*Nl*128*2);
  __hip_bfloat16* resLb2 = (__hip_bfloat16*)carve((size_t)2*Nr*128*2);
  __hip_bfloat16* W1t    = (__hip_bfloat16*)carve((size_t)2*16384*2);
  __hip_bfloat16* W2t    = (__hip_bfloat16*)carve((size_t)2*16384*2);
  float* tvec   = (float*)carve((size_t)2*Nl*384*4);
  float* sumwb  = (float*)carve((size_t)2*Nl*128*4);
  float* bneg   = (float*)carve(128*4);
  float* wln    = (float*)carve(128*4);

  int nBlkLig = (Nl + 63)/64;
  int nBlkRes = (Nr + 63)/64;

  hipLaunchKernelGGL(edgepre_kernel, dim3((E+255)/256), dim3(256), 0, stream,
                     posl, posr, el, er, ediff, proj, E, Nr);
  hipLaunchKernelGGL(prep_kernel, dim3(256), dim3(256), 0, stream,
                     Win1, Win2, W1t, W2t, bs1a, Ws1b, bs2a, Ws2b, bneg, wln);

  hipLaunchKernelGGL(pre_gemm_mfma, dim3(nBlkLig+nBlkRes, 2), dim3(256), 0, stream,
      lig, res, W1t, ligLb2, resLb2, nBlkLig, Nl, Nr);
  hipLaunchKernelGGL(h_gemm2_mfma, dim3((E+63)/64, 2), dim3(256), 0, stream,
      ligLb2, resLb2, el, er, bin1, W2t, bin2, hbuf2, E, Nl, Nr);
  hipLaunchKernelGGL(spline_kernel, dim3((E+SEPB-1)/SEPB, 2), dim3(256), 0, stream,
      hbuf2, proj, Ws1a, Ws2a, bs1b, bs2b, bneg, wln, w02b, E);
  hipLaunchKernelGGL(reduce_kernel, dim3(Nl), dim3(128), 0, stream,
      hbuf2, w02b, ediff, el, tvec, sumwb, E, Nl);
  hipLaunchKernelGGL(head_kernel, dim3(Nl), dim3(128), 0, stream,
      tvec, sumwb, Wl1, bl1, Wl2, bl2, lvin, (float*)d_out, Nl);
}

// Round 17
// 214.503 us; speedup vs baseline: 1.0159x; 1.0159x over previous
//
#include <hip/hip_runtime.h>
#include <hip/hip_bf16.h>
#include <math.h>

typedef short bf16x8 __attribute__((ext_vector_type(8)));
typedef float f32x4 __attribute__((ext_vector_type(4)));

union BU8 { uint4 u; __hip_bfloat16 h[8]; ushort s[8]; };

#define LOG2E 1.44269504f
#define LN2   0.69314718f
#define NIV3  9            // spline intervals
#define NND3  12           // nodes = NIV3 + 3  (192 tasks = 3 full waves)

// ---------- small helpers ----------
__device__ __forceinline__ float3 f3sub(float3 a, float3 b){ return make_float3(a.x-b.x, a.y-b.y, a.z-b.z); }
__device__ __forceinline__ float3 f3nrm(float3 v){
  float n = sqrtf(v.x*v.x + v.y*v.y + v.z*v.z);
  float inv = 1.0f / fmaxf(n, 1e-8f);
  return make_float3(v.x*inv, v.y*inv, v.z*inv);
}
__device__ __forceinline__ float3 f3cross(float3 a, float3 b){
  return make_float3(a.y*b.z - a.z*b.y, a.z*b.x - a.x*b.z, a.x*b.y - a.y*b.x);
}
__device__ __forceinline__ float silu_f(float x){
  float ex = __expf(-x);
  return x * __builtin_amdgcn_rcpf(1.0f + ex);
}
__device__ __forceinline__ uint packbf2(float a, float b){
  ushort ua = __bfloat16_as_ushort(__float2bfloat16(a));
  ushort ub = __bfloat16_as_ushort(__float2bfloat16(b));
  return (uint)ua | ((uint)ub << 16);
}

// ---------- kernel 1: per-edge frame (inline) + diff + proj ----------
__global__ void edgepre_kernel(const float* __restrict__ posl, const float* __restrict__ posr,
    const int* __restrict__ el, const int* __restrict__ er,
    float* __restrict__ ediff, float* __restrict__ proj, int E, int Nr){
  int e = blockIdx.x*blockDim.x + threadIdx.x;
  if (e >= E) return;
  int a = el[e], r = er[e];
  float3 pa = make_float3(posl[3*a+0], posl[3*a+1], posl[3*a+2]);
  float3 pr = make_float3(posr[3*r+0], posr[3*r+1], posr[3*r+2]);
  float3 ed = f3nrm(f3sub(pa,pr));

  int k = r - 1;
  if (k < 0) k = 0;
  int kmax = Nr - 3;
  if (k > kmax) k = kmax;
  float3 p0 = make_float3(posr[3*k+0], posr[3*k+1], posr[3*k+2]);
  float3 p1 = make_float3(posr[3*k+3], posr[3*k+4], posr[3*k+5]);
  float3 p2 = make_float3(posr[3*k+6], posr[3*k+7], posr[3*k+8]);
  float3 u0 = f3nrm(f3sub(p1,p0));
  float3 u1 = f3nrm(f3sub(p2,p1));
  float3 dif = f3nrm(f3sub(u0,u1));
  float3 cr  = f3nrm(f3cross(u0,u1));
  float3 vt  = f3nrm(f3cross(dif,cr));

  float px = ed.x*dif.x + ed.y*cr.x + ed.z*vt.x;
  float py = ed.x*dif.y + ed.y*cr.y + ed.z*vt.y;
  float pz = ed.x*dif.z + ed.y*cr.z + ed.z*vt.z;
  ediff[3*e+0]=ed.x; ediff[3*e+1]=ed.y; ediff[3*e+2]=ed.z;
  proj[3*e+0]=px; proj[3*e+1]=py; proj[3*e+2]=pz;
}

// ---------- kernel P: weight transpose+convert + exp2-folded consts ----------
__global__ void prep_kernel(const float* __restrict__ Win1, const float* __restrict__ Win2,
                            __hip_bfloat16* __restrict__ W1t, __hip_bfloat16* __restrict__ W2t,
                            const float* __restrict__ bs1a, const float* __restrict__ Ws1b,
                            const float* __restrict__ bs2a, const float* __restrict__ Ws2b,
                            float* __restrict__ bneg, float* __restrict__ wln){
  int idx = blockIdx.x*blockDim.x + threadIdx.x;
  if (idx < 32768){
    int l = idx >> 14, rem = idx & 16383, n = rem >> 7, k = rem & 127;
    W1t[idx] = __float2bfloat16(Win1[(l<<14) + (k<<7) + n]);
  } else if (idx < 65536){
    int i2 = idx - 32768;
    int l = i2 >> 14, rem = i2 & 16383, n = rem >> 7, k = rem & 127;
    W2t[i2] = __float2bfloat16(Win2[(l<<14) + (k<<7) + n]);
  }
  if (blockIdx.x == 0 && threadIdx.x < 128){
    int t = threadIdx.x;
    int l = t >> 6, br = (t >> 5) & 1, q = t & 31;
    const float* ba = br ? bs2a : bs1a;
    const float* Wb = br ? Ws2b : Ws1b;
    bneg[t] = -ba[l*32 + q] * LOG2E;
    wln[t]  = -Wb[l*32 + q] * LN2;
  }
}

// ---------- kernel 3a: MFMA pre-GEMM, B in regs, both layers (grid.y = layer) ----------
__global__ __launch_bounds__(256) void pre_gemm_mfma(
    const float* __restrict__ lig, const float* __restrict__ res,
    const __hip_bfloat16* __restrict__ W1t,
    __hip_bfloat16* __restrict__ ligLb, __hip_bfloat16* __restrict__ resLb,
    int nBlkLig, int Nl, int Nr)
{
  __shared__ __hip_bfloat16 sA[64][136];
  int b = blockIdx.x;
  int layer = blockIdx.y;
  const __hip_bfloat16* Wt = W1t + (size_t)layer*16384;
  const float* X; __hip_bfloat16* O; int row0, rows;
  if (b < nBlkLig){ X = lig; O = ligLb + (size_t)layer*Nl*128; row0 = b*64;           rows = Nl; }
  else            { X = res; O = resLb + (size_t)layer*Nr*128; row0 = (b-nBlkLig)*64; rows = Nr; }
  int tid = threadIdx.x;
  int w = tid >> 6, l = tid & 63;
  int lrow = l & 15, lko = (l >> 4) * 8;

  bf16x8 breg[4][2];
  #pragma unroll
  for (int kc4 = 0; kc4 < 4; ++kc4){
    #pragma unroll
    for (int nt = 0; nt < 2; ++nt)
      breg[kc4][nt] = *(const bf16x8*)((const ushort*)Wt + (w*32+nt*16+lrow)*128 + kc4*32 + lko);
  }

  {
    int r = tid >> 2, p = tid & 3, cb = p*32;
    int row = row0 + r; if (row >= rows) row = rows - 1;
    const float* src = X + (size_t)row*128 + cb;
    ushort* dst = (ushort*)&sA[r][0] + cb;
    #pragma unroll
    for (int i = 0; i < 32; i += 8){
      float4 v0 = *(const float4*)(src + i);
      float4 v1 = *(const float4*)(src + i + 4);
      BU8 o;
      o.h[0]=__float2bfloat16(v0.x); o.h[1]=__float2bfloat16(v0.y);
      o.h[2]=__float2bfloat16(v0.z); o.h[3]=__float2bfloat16(v0.w);
      o.h[4]=__float2bfloat16(v1.x); o.h[5]=__float2bfloat16(v1.y);
      o.h[6]=__float2bfloat16(v1.z); o.h[7]=__float2bfloat16(v1.w);
      *(uint4*)(dst + i) = o.u;
    }
  }
  __syncthreads();

  f32x4 acc[4][2];
  for (int mt=0; mt<4; ++mt)
    for (int nt=0; nt<2; ++nt)
      acc[mt][nt] = (f32x4){0.f,0.f,0.f,0.f};

  #pragma unroll
  for (int kc4 = 0; kc4 < 4; ++kc4){
    bf16x8 af[4];
    #pragma unroll
    for (int mt=0; mt<4; ++mt)
      af[mt] = *(const bf16x8*)((const ushort*)&sA[0][0] + (mt*16+lrow)*136 + kc4*32 + lko);
    #pragma unroll
    for (int mt=0; mt<4; ++mt){
      #pragma unroll
      for (int nt=0; nt<2; ++nt)
        acc[mt][nt] = __builtin_amdgcn_mfma_f32_16x16x32_bf16(af[mt], breg[kc4][nt], acc[mt][nt], 0, 0, 0);
    }
  }

  int orow = (l >> 4) * 4;
  #pragma unroll
  for (int mt=0; mt<4; ++mt){
    #pragma unroll
    for (int nt=0; nt<2; ++nt){
      int n = w*32 + nt*16 + (l & 15);
      #pragma unroll
      for (int j=0; j<4; ++j){
        int row = row0 + mt*16 + orow + j;
        if (row < rows) O[(size_t)row*128 + n] = __float2bfloat16(acc[mt][nt][j]);
      }
    }
  }
}

// ---------- kernel 3b: h-GEMM, B in regs, both layers (grid.y = layer) ----------
__global__ __launch_bounds__(256) void h_gemm2_mfma(
    const __hip_bfloat16* __restrict__ ligLbB, const __hip_bfloat16* __restrict__ resLbB,
    const int* __restrict__ el, const int* __restrict__ er,
    const float* __restrict__ b1B, const __hip_bfloat16* __restrict__ W2tB,
    const float* __restrict__ b2B,
    __hip_bfloat16* __restrict__ houtB, int E, int Nl, int Nr)
{
  __shared__ __hip_bfloat16 sA[64][136];
  int tid = threadIdx.x;
  int e0 = blockIdx.x * 64;
  int layer = blockIdx.y;
  const __hip_bfloat16* ligLb = ligLbB + (size_t)layer*Nl*128;
  const __hip_bfloat16* resLb = resLbB + (size_t)layer*Nr*128;
  const float* b1 = b1B + layer*128;
  const __hip_bfloat16* W2t = W2tB + (size_t)layer*16384;
  const float* b2 = b2B + layer*128;
  __hip_bfloat16* hout = houtB + (size_t)layer*E*128;

  int w = tid >> 6, l = tid & 63;
  int lrow = l & 15, lko = (l >> 4) * 8;

  bf16x8 breg[4][2];
  #pragma unroll
  for (int kc4 = 0; kc4 < 4; ++kc4){
    #pragma unroll
    for (int nt = 0; nt < 2; ++nt)
      breg[kc4][nt] = *(const bf16x8*)((const ushort*)W2t + (w*32+nt*16+lrow)*128 + kc4*32 + lko);
  }

  {
    int r = tid >> 2, p = tid & 3, cb = p*32;
    int e = e0 + r; if (e >= E) e = E - 1;
    const ushort* la = (const ushort*)ligLb + (size_t)el[e]*128 + cb;
    const ushort* ra = (const ushort*)resLb + (size_t)er[e]*128 + cb;
    ushort* dst = (ushort*)&sA[r][0] + cb;
    #pragma unroll
    for (int i = 0; i < 32; i += 8){
      BU8 A, B, O;
      A.u = *(const uint4*)(la + i);
      B.u = *(const uint4*)(ra + i);
      float4 bb0 = *(const float4*)(b1 + cb + i);
      float4 bbx = *(const float4*)(b1 + cb + i + 4);
      float bbs[8] = {bb0.x,bb0.y,bb0.z,bb0.w,bbx.x,bbx.y,bbx.z,bbx.w};
      #pragma unroll
      for (int j=0; j<8; ++j){
        float x = __bfloat162float(A.h[j]) + __bfloat162float(B.h[j]) + bbs[j];
        O.h[j] = __float2bfloat16(silu_f(x));
      }
      *(uint4*)(dst + i) = O.u;
    }
  }
  __syncthreads();

  f32x4 acc[4][2];
  for (int mt=0; mt<4; ++mt)
    for (int nt=0; nt<2; ++nt)
      acc[mt][nt] = (f32x4){0.f,0.f,0.f,0.f};

  #pragma unroll
  for (int kc4 = 0; kc4 < 4; ++kc4){
    bf16x8 af[4];
    #pragma unroll
    for (int mt=0; mt<4; ++mt)
      af[mt] = *(const bf16x8*)((const ushort*)&sA[0][0] + (mt*16+lrow)*136 + kc4*32 + lko);
    #pragma unroll
    for (int mt=0; mt<4; ++mt){
      #pragma unroll
      for (int nt=0; nt<2; ++nt)
        acc[mt][nt] = __builtin_amdgcn_mfma_f32_16x16x32_bf16(af[mt], breg[kc4][nt], acc[mt][nt], 0, 0, 0);
    }
  }

  int orow = (l >> 4) * 4;
  #pragma unroll
  for (int mt=0; mt<4; ++mt){
    #pragma unroll
    for (int nt=0; nt<2; ++nt){
      int n = w*32 + nt*16 + (l & 15);
      float bb = b2[n];
      #pragma unroll
      for (int j=0; j<4; ++j){
        int e = e0 + mt*16 + orow + j;
        if (e < E) hout[(size_t)e*128 + n] = __float2bfloat16(acc[mt][nt][j] + bb);
      }
    }
  }
}

// ---------- kernel 4a: per-edge Catmull-Rom spline + inline eval -> wpair ----------
// f32 coeffs in LDS (no decode in P3); writes interleaved (w1|w2) uint per (e,d).
#define SEPB 16
__global__ __launch_bounds__(256) void spline_kernel(
    const __hip_bfloat16* __restrict__ hbufB, const float* __restrict__ proj,
    const float* __restrict__ Ws1a, const float* __restrict__ Ws2a,
    const float* __restrict__ bs1b, const float* __restrict__ bs2b,
    const float* __restrict__ bnegB, const float* __restrict__ wlnB,
    uint* __restrict__ wpairB, int E)
{
  int layer = blockIdx.y;
  const float* Wa1 = Ws1a + layer*96;
  const float* Wa2 = Ws2a + layer*96;
  const float* bneg = bnegB + layer*64;
  const float* wln  = wlnB  + layer*64;
  float bb1v = bs1b[layer], bb2v = bs2b[layer];
  const __hip_bfloat16* hb = hbufB + (size_t)layer*E*128;
  uint* wp = wpairB + (size_t)layer*E*128;

  __shared__ float sA[2][SEPB][36];
  __shared__ float sNF[SEPB][2][NND3];
  __shared__ ushort sH[SEPB][128];
  __shared__ f32x4 sCo[SEPB][2][NIV3];
  __shared__ float sMin[SEPB], sMax[SEPB];
  __shared__ float sH0[SEPB], sDv[SEPB], sInvD[SEPB], sP0[SEPB];

  int tid = threadIdx.x;
  int eb0 = blockIdx.x * SEPB;

  // P1: stage h rows + per-edge min/max (16 threads/edge)
  {
    int et = tid >> 4, sg = tid & 15;
    int e = eb0 + et; if (e >= E) e = E-1;
    uint4 raw = *(const uint4*)((const ushort*)hb + (size_t)e*128 + sg*8);
    *(uint4*)&sH[et][sg*8] = raw;
    uint us[4] = {raw.x, raw.y, raw.z, raw.w};
    float mn = 1e30f, mx = -1e30f;
    #pragma unroll
    for (int i=0;i<4;i++){
      float lo = __uint_as_float(us[i]<<16);
      float hi = __uint_as_float(us[i]&0xFFFF0000u);
      mn = fminf(mn, fminf(lo,hi)); mx = fmaxf(mx, fmaxf(lo,hi));
    }
    #pragma unroll
    for (int o=8;o>0;o>>=1){ mn=fminf(mn,__shfl_xor(mn,o)); mx=fmaxf(mx,__shfl_xor(mx,o)); }
    if (sg==0){ sMin[et]=mn; sMax[et]=mx; }
  }
  __syncthreads();

  // P1b: per-edge A'_q (folded -log2e) + scalars
  for (int t=tid; t<2*SEPB*32; t+=256){
    int et = t>>6, rem = t&63, br = rem>>5, q = rem&31;
    int e = eb0+et; if (e>=E) e=E-1;
    const float* Wa = br ? Wa2 : Wa1;
    float p0=proj[3*e], p1=proj[3*e+1], p2=proj[3*e+2];
    sA[br][et][q] = -(p0*Wa[q]+p1*Wa[32+q]+p2*Wa[64+q])*LOG2E;
  }
  if (tid < SEPB){
    int e = eb0+tid; if (e>=E) e=E-1;
    float range = fmaxf(sMax[tid]-sMin[tid], 1e-3f);
    sH0[tid]=sMin[tid]; sDv[tid]=range*(1.0f/NIV3); sInvD[tid]=(float)NIV3/range;
    sP0[tid]=proj[3*e];
  }
  __syncthreads();

  // P2: value-only node f at 12 nodes (192 tasks = 3 waves; wave 3 skips)
  if (tid < SEPB*NND3){
    int et = tid / NND3, nd = tid - et*NND3;
    float hn = fmaf((float)(nd-1), sDv[et], sH0[et]);
    const float* A0 = &sA[0][et][0];
    const float* A1 = &sA[1][et][0];
    float f0 = 0.f, f1 = 0.f;
    #pragma unroll
    for (int q = 0; q < 32; ++q){
      float x0 = fmaf(hn, A0[q], bneg[q]);
      float x1 = fmaf(hn, A1[q], bneg[32+q]);
      float e0 = __builtin_amdgcn_exp2f(x0);
      float e1 = __builtin_amdgcn_exp2f(x1);
      float d0 = 1.0f + e0, d1 = 1.0f + e1;
      float r  = __builtin_amdgcn_rcpf(d0*d1);
      f0 = fmaf(wln[q],    x0*(r*d1), f0);
      f1 = fmaf(wln[32+q], x1*(r*d0), f1);
    }
    sNF[et][0][nd] = f0;
    sNF[et][1][nd] = f1;
  }
  __syncthreads();

  // P2.5: Catmull-Rom coeffs, f32 (9 intervals x 2 br x 16 edges = 288 tasks)
  for (int t=tid; t<2*SEPB*NIV3; t+=256){
    int et = t/(2*NIV3), rem = t - et*(2*NIV3), br = rem/NIV3, i = rem - br*NIV3;
    const float* F = &sNF[et][br][0];
    float P0=F[i], P1=F[i+1], P2=F[i+2], P3=F[i+3];
    float bb = br ? bb2v : bb1v;
    f32x4 C;
    C[0] = P1 + bb;
    C[1] = 0.5f*(P2 - P0);
    C[2] = P0 - 2.5f*P1 + 2.0f*P2 - 0.5f*P3;
    C[3] = 0.5f*(P3 - P0) + 1.5f*(P1 - P2);
    sCo[et][br][i] = C;
  }
  __syncthreads();

  // P3: inline eval — 512 tasks (16 edges x 32 groups of 4 channels) -> wpair
  for (int t=tid; t<512; t+=256){
    int et = t>>5, g = t&31;
    int e = eb0 + et;
    if (e < E){
      int d0 = g*4;
      ushort4 hv4 = *(const ushort4*)&sH[et][d0];
      float h0=sH0[et], invD=sInvD[et], p0=sP0[et];
      ushort hvs[4] = {hv4.x, hv4.y, hv4.z, hv4.w};
      uint outp[4];
      #pragma unroll
      for (int k=0;k<4;++k){
        float h = __uint_as_float(((uint)hvs[k])<<16);
        float u = (h - h0) * invD;
        int ii = (int)u; ii = ii < 0 ? 0 : (ii > NIV3-1 ? NIV3-1 : ii);
        float s = u - (float)ii;
        f32x4 CA = sCo[et][0][ii];
        f32x4 CB = sCo[et][1][ii];
        float v1 = fmaf(fmaf(fmaf(CA[3],s,CA[2]),s,CA[1]),s,CA[0]);
        float v2 = fmaf(fmaf(fmaf(CB[3],s,CB[2]),s,CB[1]),s,CB[0]);
        float hp = h * p0;
        outp[k] = packbf2(v1 + hp, v2 + hp);
      }
      uint4 O = {outp[0], outp[1], outp[2], outp[3]};
      *(uint4*)(wp + (size_t)e*128 + d0) = O;
    }
  }
}

// ---------- kernel 4b: per-atom streaming reduce, BOTH layers per block ----------
__global__ __launch_bounds__(128) void reduce_kernel(
    const uint* __restrict__ wpairB,
    const float* __restrict__ ediff, const int* __restrict__ el,
    float* __restrict__ tvec, float* __restrict__ sumwb, int E, int Nl)
{
  __shared__ float sEd[64][3];
  int a = blockIdx.x;
  int d = threadIdx.x;
  const uint* wpL0 = wpairB;
  const uint* wpL1 = wpairB + (size_t)E*128;

  int lo = 0, hi = E;
  while (lo < hi){ int m = (lo+hi)>>1; if (el[m] < a) lo = m+1; else hi = m; }
  int estart = lo;
  int lo2 = lo, hi2 = E;
  while (lo2 < hi2){ int m = (lo2+hi2)>>1; if (el[m] <= a) lo2 = m+1; else hi2 = m; }
  int eend = lo2;

  float s0=0.f, tx0=0.f, ty0=0.f, tz0=0.f;
  float s1=0.f, tx1=0.f, ty1=0.f, tz1=0.f;

  for (int ebase = estart; ebase < eend; ebase += 64){
    int n = min(64, eend - ebase);
    __syncthreads();
    for (int t = d; t < n*3; t += 128)
      ((float*)sEd)[t] = ediff[(size_t)ebase*3 + t];
    __syncthreads();

    #pragma unroll 4
    for (int ei = 0; ei < n; ++ei){
      size_t idx = (size_t)(ebase+ei)*128 + d;
      uint u0v = wpL0[idx];
      uint u1v = wpL1[idx];
      float a1 = __uint_as_float(u0v << 16);
      float b1 = __uint_as_float(u0v & 0xFFFF0000u);
      float a2 = __uint_as_float(u1v << 16);
      float b2 = __uint_as_float(u1v & 0xFFFF0000u);
      float ex = sEd[ei][0], ey = sEd[ei][1], ez = sEd[ei][2];
      s0 += a1;  s1 += a2;
      tx0 = fmaf(ex, b1, tx0);  tx1 = fmaf(ex, b2, tx1);
      ty0 = fmaf(ey, b1, ty0);  ty1 = fmaf(ey, b2, ty1);
      tz0 = fmaf(ez, b1, tz0);  tz1 = fmaf(ez, b2, tz1);
    }
  }

  size_t t0b = (size_t)a*384 + d;
  tvec[t0b      ] = tx0;
  tvec[t0b + 128] = ty0;
  tvec[t0b + 256] = tz0;
  size_t t1b = (size_t)Nl*384 + t0b;
  tvec[t1b      ] = tx1;
  tvec[t1b + 128] = ty1;
  tvec[t1b + 256] = tz1;
  sumwb[(size_t)a*128 + d] = s0;
  sumwb[(size_t)Nl*128 + (size_t)a*128 + d] = s1;
}

// ---------- kernel 5: combine (lv = t0*(1+sumw1)+t1) + head ----------
__global__ __launch_bounds__(128) void head_kernel(
    const float* __restrict__ tvec, const float* __restrict__ sumwb,
    const float* __restrict__ Wl1, const float* __restrict__ bl1,
    const float* __restrict__ Wl2, const float* __restrict__ bl2,
    const float* __restrict__ lvin, float* __restrict__ out, int Nl)
{
  int a = blockIdx.x, d = threadIdx.x;
  __shared__ float slv[3][128];
  __shared__ float sred[2][3];
  const float* t0 = tvec + (size_t)a*384;
  const float* t1 = tvec + (size_t)Nl*384 + (size_t)a*384;
  float m = 1.0f + sumwb[(size_t)Nl*128 + (size_t)a*128 + d];
  slv[0][d] = t0[d      ]*m + t1[d      ];
  slv[1][d] = t0[d + 128]*m + t1[d + 128];
  slv[2][d] = t0[d + 256]*m + t1[d + 256];
  __syncthreads();
  float b = bl1[d];
  float a0 = b, a1 = b, a2 = b;
  #pragma unroll 4
  for (int k = 0; k < 128; ++k) {
    float w = Wl1[k*128 + d];
    a0 = fmaf(slv[0][k], w, a0);
    a1 = fmaf(slv[1][k], w, a1);
    a2 = fmaf(slv[2][k], w, a2);
  }
  float wl2 = Wl2[d];
  float z0 = fmaxf(a0, 0.f)*wl2;
  float z1 = fmaxf(a1, 0.f)*wl2;
  float z2 = fmaxf(a2, 0.f)*wl2;
  #pragma unroll
  for (int off = 32; off > 0; off >>= 1) {
    z0 += __shfl_down(z0, off);
    z1 += __shfl_down(z1, off);
    z2 += __shfl_down(z2, off);
  }
  int wv = d >> 6;
  if ((d & 63) == 0) { sred[wv][0]=z0; sred[wv][1]=z1; sred[wv][2]=z2; }
  __syncthreads();
  if (d == 0) {
    float bb = bl2[0];
    out[a*3+0] = sred[0][0]+sred[1][0] + bb + lvin[a*3+0];
    out[a*3+1] = sred[0][1]+sred[1][1] + bb + lvin[a*3+1];
    out[a*3+2] = sred[0][2]+sred[1][2] + bb + lvin[a*3+2];
  }
}

// ---------- launcher ----------
extern "C" void kernel_launch(void* const* d_in, const int* in_sizes, int n_in,
                              void* d_out, int out_size, void* d_ws, size_t ws_size,
                              hipStream_t stream)
{
  const float* lig   = (const float*)d_in[0];
  const float* lvin  = (const float*)d_in[1];
  const float* posl  = (const float*)d_in[2];
  const float* res   = (const float*)d_in[3];
  const float* posr  = (const float*)d_in[4];
  const int*   el    = (const int*)d_in[7];
  const int*   er    = (const int*)d_in[8];
  const float* Win1  = (const float*)d_in[9];
  const float* bin1  = (const float*)d_in[10];
  const float* Win2  = (const float*)d_in[11];
  const float* bin2  = (const float*)d_in[12];
  const float* Ws1a  = (const float*)d_in[13];
  const float* bs1a  = (const float*)d_in[14];
  const float* Ws1b  = (const float*)d_in[15];
  const float* bs1b  = (const float*)d_in[16];
  const float* Ws2a  = (const float*)d_in[17];
  const float* bs2a  = (const float*)d_in[18];
  const float* Ws2b  = (const float*)d_in[19];
  const float* bs2b  = (const float*)d_in[20];
  const float* Wl1   = (const float*)d_in[21];
  const float* bl1   = (const float*)d_in[22];
  const float* Wl2   = (const float*)d_in[23];
  const float* bl2   = (const float*)d_in[24];

  int Nl = in_sizes[2] / 3;
  int Nr = in_sizes[4] / 3;
  int E  = in_sizes[7];

  char* wsb = (char*)d_ws;
  size_t off = 0;
  auto carve = [&](size_t bytes) -> char* {
    char* p = wsb + off;
    off += (bytes + 255) & ~(size_t)255;
    return p;
  };
  float* ediff  = (float*)carve((size_t)E*3*4);
  float* proj   = (float*)carve((size_t)E*3*4);
  __hip_bfloat16* hbuf2  = (__hip_bfloat16*)carve((size_t)2*E*128*2);
  uint* wpair   = (uint*)carve((size_t)2*E*128*4);
  __hip_bfloat16* ligLb2 = (__hip_bfloat16*)carve((size_t)2*Nl*128*2);
  __hip_bfloat16* resLb2 = (__hip_bfloat16*)carve((size_t)2*Nr*128*2);
  __hip_bfloat16* W1t    = (__hip_bfloat16*)carve((size_t)2*16384*2);
  __hip_bfloat16* W2t    = (__hip_bfloat16*)carve((size_t)2*16384*2);
  float* tvec   = (float*)carve((size_t)2*Nl*384*4);
  float* sumwb  = (float*)carve((size_t)2*Nl*128*4);
  float* bneg   = (float*)carve(128*4);
  float* wln    = (float*)carve(128*4);

  int nBlkLig = (Nl + 63)/64;
  int nBlkRes = (Nr + 63)/64;

  hipLaunchKernelGGL(edgepre_kernel, dim3((E+255)/256), dim3(256), 0, stream,
                     posl, posr, el, er, ediff, proj, E, Nr);
  hipLaunchKernelGGL(prep_kernel, dim3(256), dim3(256), 0, stream,
                     Win1, Win2, W1t, W2t, bs1a, Ws1b, bs2a, Ws2b, bneg, wln);

  hipLaunchKernelGGL(pre_gemm_mfma, dim3(nBlkLig+nBlkRes, 2), dim3(256), 0, stream,
      lig, res, W1t, ligLb2, resLb2, nBlkLig, Nl, Nr);
  hipLaunchKernelGGL(h_gemm2_mfma, dim3((E+63)/64, 2), dim3(256), 0, stream,
      ligLb2, resLb2, el, er, bin1, W2t, bin2, hbuf2, E, Nl, Nr);
  hipLaunchKernelGGL(spline_kernel, dim3((E+SEPB-1)/SEPB, 2), dim3(256), 0, stream,
      hbuf2, proj, Ws1a, Ws2a, bs1b, bs2b, bneg, wln, wpair, E);
  hipLaunchKernelGGL(reduce_kernel, dim3(Nl), dim3(128), 0, stream,
      wpair, ediff, el, tvec, sumwb, E, Nl);
  hipLaunchKernelGGL(head_kernel, dim3(Nl), dim3(128), 0, stream,
      tvec, sumwb, Wl1, bl1, Wl2, bl2, lvin, (float*)d_out, Nl);
}

// Round 18
// 201.902 us; speedup vs baseline: 1.0793x; 1.0624x over previous
//
#include <hip/hip_runtime.h>
#include <hip/hip_bf16.h>
#include <math.h>

typedef short bf16x8 __attribute__((ext_vector_type(8)));
typedef float f32x4 __attribute__((ext_vector_type(4)));

union BU8 { uint4 u; __hip_bfloat16 h[8]; ushort s[8]; };

#define LOG2E 1.44269504f
#define LN2   0.69314718f
#define NIV3  5            // spline intervals
#define NND3  8            // nodes = NIV3 + 3  (128 tasks = 2 full waves)

// ---------- small helpers ----------
__device__ __forceinline__ float3 f3sub(float3 a, float3 b){ return make_float3(a.x-b.x, a.y-b.y, a.z-b.z); }
__device__ __forceinline__ float3 f3nrm(float3 v){
  float n = sqrtf(v.x*v.x + v.y*v.y + v.z*v.z);
  float inv = 1.0f / fmaxf(n, 1e-8f);
  return make_float3(v.x*inv, v.y*inv, v.z*inv);
}
__device__ __forceinline__ float3 f3cross(float3 a, float3 b){
  return make_float3(a.y*b.z - a.z*b.y, a.z*b.x - a.x*b.z, a.x*b.y - a.y*b.x);
}
__device__ __forceinline__ float silu_f(float x){
  float ex = __expf(-x);
  return x * __builtin_amdgcn_rcpf(1.0f + ex);
}
__device__ __forceinline__ uint packbf2(float a, float b){
  ushort ua = __bfloat16_as_ushort(__float2bfloat16(a));
  ushort ub = __bfloat16_as_ushort(__float2bfloat16(b));
  return (uint)ua | ((uint)ub << 16);
}

// ---------- kernel 1: per-edge frame (inline) + diff + proj ----------
__global__ void edgepre_kernel(const float* __restrict__ posl, const float* __restrict__ posr,
    const int* __restrict__ el, const int* __restrict__ er,
    float* __restrict__ ediff, float* __restrict__ proj, int E, int Nr){
  int e = blockIdx.x*blockDim.x + threadIdx.x;
  if (e >= E) return;
  int a = el[e], r = er[e];
  float3 pa = make_float3(posl[3*a+0], posl[3*a+1], posl[3*a+2]);
  float3 pr = make_float3(posr[3*r+0], posr[3*r+1], posr[3*r+2]);
  float3 ed = f3nrm(f3sub(pa,pr));

  int k = r - 1;
  if (k < 0) k = 0;
  int kmax = Nr - 3;
  if (k > kmax) k = kmax;
  float3 p0 = make_float3(posr[3*k+0], posr[3*k+1], posr[3*k+2]);
  float3 p1 = make_float3(posr[3*k+3], posr[3*k+4], posr[3*k+5]);
  float3 p2 = make_float3(posr[3*k+6], posr[3*k+7], posr[3*k+8]);
  float3 u0 = f3nrm(f3sub(p1,p0));
  float3 u1 = f3nrm(f3sub(p2,p1));
  float3 dif = f3nrm(f3sub(u0,u1));
  float3 cr  = f3nrm(f3cross(u0,u1));
  float3 vt  = f3nrm(f3cross(dif,cr));

  float px = ed.x*dif.x + ed.y*cr.x + ed.z*vt.x;
  float py = ed.x*dif.y + ed.y*cr.y + ed.z*vt.y;
  float pz = ed.x*dif.z + ed.y*cr.z + ed.z*vt.z;
  ediff[3*e+0]=ed.x; ediff[3*e+1]=ed.y; ediff[3*e+2]=ed.z;
  proj[3*e+0]=px; proj[3*e+1]=py; proj[3*e+2]=pz;
}

// ---------- kernel P: weight transpose+convert + exp2-folded consts ----------
__global__ void prep_kernel(const float* __restrict__ Win1, const float* __restrict__ Win2,
                            __hip_bfloat16* __restrict__ W1t, __hip_bfloat16* __restrict__ W2t,
                            const float* __restrict__ bs1a, const float* __restrict__ Ws1b,
                            const float* __restrict__ bs2a, const float* __restrict__ Ws2b,
                            float* __restrict__ bneg, float* __restrict__ wln){
  int idx = blockIdx.x*blockDim.x + threadIdx.x;
  if (idx < 32768){
    int l = idx >> 14, rem = idx & 16383, n = rem >> 7, k = rem & 127;
    W1t[idx] = __float2bfloat16(Win1[(l<<14) + (k<<7) + n]);
  } else if (idx < 65536){
    int i2 = idx - 32768;
    int l = i2 >> 14, rem = i2 & 16383, n = rem >> 7, k = rem & 127;
    W2t[i2] = __float2bfloat16(Win2[(l<<14) + (k<<7) + n]);
  }
  if (blockIdx.x == 0 && threadIdx.x < 128){
    int t = threadIdx.x;
    int l = t >> 6, br = (t >> 5) & 1, q = t & 31;
    const float* ba = br ? bs2a : bs1a;
    const float* Wb = br ? Ws2b : Ws1b;
    bneg[t] = -ba[l*32 + q] * LOG2E;
    wln[t]  = -Wb[l*32 + q] * LN2;
  }
}

// ---------- kernel 3a: MFMA pre-GEMM, B in regs, both layers (grid.y = layer) ----------
__global__ __launch_bounds__(256) void pre_gemm_mfma(
    const float* __restrict__ lig, const float* __restrict__ res,
    const __hip_bfloat16* __restrict__ W1t,
    __hip_bfloat16* __restrict__ ligLb, __hip_bfloat16* __restrict__ resLb,
    int nBlkLig, int Nl, int Nr)
{
  __shared__ __hip_bfloat16 sA[64][136];
  int b = blockIdx.x;
  int layer = blockIdx.y;
  const __hip_bfloat16* Wt = W1t + (size_t)layer*16384;
  const float* X; __hip_bfloat16* O; int row0, rows;
  if (b < nBlkLig){ X = lig; O = ligLb + (size_t)layer*Nl*128; row0 = b*64;           rows = Nl; }
  else            { X = res; O = resLb + (size_t)layer*Nr*128; row0 = (b-nBlkLig)*64; rows = Nr; }
  int tid = threadIdx.x;
  int w = tid >> 6, l = tid & 63;
  int lrow = l & 15, lko = (l >> 4) * 8;

  bf16x8 breg[4][2];
  #pragma unroll
  for (int kc4 = 0; kc4 < 4; ++kc4){
    #pragma unroll
    for (int nt = 0; nt < 2; ++nt)
      breg[kc4][nt] = *(const bf16x8*)((const ushort*)Wt + (w*32+nt*16+lrow)*128 + kc4*32 + lko);
  }

  {
    int r = tid >> 2, p = tid & 3, cb = p*32;
    int row = row0 + r; if (row >= rows) row = rows - 1;
    const float* src = X + (size_t)row*128 + cb;
    ushort* dst = (ushort*)&sA[r][0] + cb;
    #pragma unroll
    for (int i = 0; i < 32; i += 8){
      float4 v0 = *(const float4*)(src + i);
      float4 v1 = *(const float4*)(src + i + 4);
      BU8 o;
      o.h[0]=__float2bfloat16(v0.x); o.h[1]=__float2bfloat16(v0.y);
      o.h[2]=__float2bfloat16(v0.z); o.h[3]=__float2bfloat16(v0.w);
      o.h[4]=__float2bfloat16(v1.x); o.h[5]=__float2bfloat16(v1.y);
      o.h[6]=__float2bfloat16(v1.z); o.h[7]=__float2bfloat16(v1.w);
      *(uint4*)(dst + i) = o.u;
    }
  }
  __syncthreads();

  f32x4 acc[4][2];
  for (int mt=0; mt<4; ++mt)
    for (int nt=0; nt<2; ++nt)
      acc[mt][nt] = (f32x4){0.f,0.f,0.f,0.f};

  #pragma unroll
  for (int kc4 = 0; kc4 < 4; ++kc4){
    bf16x8 af[4];
    #pragma unroll
    for (int mt=0; mt<4; ++mt)
      af[mt] = *(const bf16x8*)((const ushort*)&sA[0][0] + (mt*16+lrow)*136 + kc4*32 + lko);
    #pragma unroll
    for (int mt=0; mt<4; ++mt){
      #pragma unroll
      for (int nt=0; nt<2; ++nt)
        acc[mt][nt] = __builtin_amdgcn_mfma_f32_16x16x32_bf16(af[mt], breg[kc4][nt], acc[mt][nt], 0, 0, 0);
    }
  }

  int orow = (l >> 4) * 4;
  #pragma unroll
  for (int mt=0; mt<4; ++mt){
    #pragma unroll
    for (int nt=0; nt<2; ++nt){
      int n = w*32 + nt*16 + (l & 15);
      #pragma unroll
      for (int j=0; j<4; ++j){
        int row = row0 + mt*16 + orow + j;
        if (row < rows) O[(size_t)row*128 + n] = __float2bfloat16(acc[mt][nt][j]);
      }
    }
  }
}

// ---------- kernel 3b: h-GEMM, B in regs, both layers (grid.y = layer) ----------
__global__ __launch_bounds__(256) void h_gemm2_mfma(
    const __hip_bfloat16* __restrict__ ligLbB, const __hip_bfloat16* __restrict__ resLbB,
    const int* __restrict__ el, const int* __restrict__ er,
    const float* __restrict__ b1B, const __hip_bfloat16* __restrict__ W2tB,
    const float* __restrict__ b2B,
    __hip_bfloat16* __restrict__ houtB, int E, int Nl, int Nr)
{
  __shared__ __hip_bfloat16 sA[64][136];
  int tid = threadIdx.x;
  int e0 = blockIdx.x * 64;
  int layer = blockIdx.y;
  const __hip_bfloat16* ligLb = ligLbB + (size_t)layer*Nl*128;
  const __hip_bfloat16* resLb = resLbB + (size_t)layer*Nr*128;
  const float* b1 = b1B + layer*128;
  const __hip_bfloat16* W2t = W2tB + (size_t)layer*16384;
  const float* b2 = b2B + layer*128;
  __hip_bfloat16* hout = houtB + (size_t)layer*E*128;

  int w = tid >> 6, l = tid & 63;
  int lrow = l & 15, lko = (l >> 4) * 8;

  bf16x8 breg[4][2];
  #pragma unroll
  for (int kc4 = 0; kc4 < 4; ++kc4){
    #pragma unroll
    for (int nt = 0; nt < 2; ++nt)
      breg[kc4][nt] = *(const bf16x8*)((const ushort*)W2t + (w*32+nt*16+lrow)*128 + kc4*32 + lko);
  }

  {
    int r = tid >> 2, p = tid & 3, cb = p*32;
    int e = e0 + r; if (e >= E) e = E - 1;
    const ushort* la = (const ushort*)ligLb + (size_t)el[e]*128 + cb;
    const ushort* ra = (const ushort*)resLb + (size_t)er[e]*128 + cb;
    ushort* dst = (ushort*)&sA[r][0] + cb;
    #pragma unroll
    for (int i = 0; i < 32; i += 8){
      BU8 A, B, O;
      A.u = *(const uint4*)(la + i);
      B.u = *(const uint4*)(ra + i);
      float4 bb0 = *(const float4*)(b1 + cb + i);
      float4 bbx = *(const float4*)(b1 + cb + i + 4);
      float bbs[8] = {bb0.x,bb0.y,bb0.z,bb0.w,bbx.x,bbx.y,bbx.z,bbx.w};
      #pragma unroll
      for (int j=0; j<8; ++j){
        float x = __bfloat162float(A.h[j]) + __bfloat162float(B.h[j]) + bbs[j];
        O.h[j] = __float2bfloat16(silu_f(x));
      }
      *(uint4*)(dst + i) = O.u;
    }
  }
  __syncthreads();

  f32x4 acc[4][2];
  for (int mt=0; mt<4; ++mt)
    for (int nt=0; nt<2; ++nt)
      acc[mt][nt] = (f32x4){0.f,0.f,0.f,0.f};

  #pragma unroll
  for (int kc4 = 0; kc4 < 4; ++kc4){
    bf16x8 af[4];
    #pragma unroll
    for (int mt=0; mt<4; ++mt)
      af[mt] = *(const bf16x8*)((const ushort*)&sA[0][0] + (mt*16+lrow)*136 + kc4*32 + lko);
    #pragma unroll
    for (int mt=0; mt<4; ++mt){
      #pragma unroll
      for (int nt=0; nt<2; ++nt)
        acc[mt][nt] = __builtin_amdgcn_mfma_f32_16x16x32_bf16(af[mt], breg[kc4][nt], acc[mt][nt], 0, 0, 0);
    }
  }

  int orow = (l >> 4) * 4;
  #pragma unroll
  for (int mt=0; mt<4; ++mt){
    #pragma unroll
    for (int nt=0; nt<2; ++nt){
      int n = w*32 + nt*16 + (l & 15);
      float bb = b2[n];
      #pragma unroll
      for (int j=0; j<4; ++j){
        int e = e0 + mt*16 + orow + j;
        if (e < E) hout[(size_t)e*128 + n] = __float2bfloat16(acc[mt][nt][j] + bb);
      }
    }
  }
}

// ---------- kernel 4a: per-edge Catmull-Rom spline + inline eval -> wpair ----------
// 8 nodes / 5 intervals: node phase = 128 tasks = exactly 2 waves. f32 coeffs.
#define SEPB 16
__global__ __launch_bounds__(256) void spline_kernel(
    const __hip_bfloat16* __restrict__ hbufB, const float* __restrict__ proj,
    const float* __restrict__ Ws1a, const float* __restrict__ Ws2a,
    const float* __restrict__ bs1b, const float* __restrict__ bs2b,
    const float* __restrict__ bnegB, const float* __restrict__ wlnB,
    uint* __restrict__ wpairB, int E)
{
  int layer = blockIdx.y;
  const float* Wa1 = Ws1a + layer*96;
  const float* Wa2 = Ws2a + layer*96;
  const float* bneg = bnegB + layer*64;
  const float* wln  = wlnB  + layer*64;
  float bb1v = bs1b[layer], bb2v = bs2b[layer];
  const __hip_bfloat16* hb = hbufB + (size_t)layer*E*128;
  uint* wp = wpairB + (size_t)layer*E*128;

  __shared__ float sA[2][SEPB][36];
  __shared__ float sNF[SEPB][2][NND3];
  __shared__ ushort sH[SEPB][128];
  __shared__ f32x4 sCo[SEPB][2][NIV3];
  __shared__ float sMin[SEPB], sMax[SEPB];
  __shared__ float sH0[SEPB], sDv[SEPB], sInvD[SEPB], sP0[SEPB];

  int tid = threadIdx.x;
  int eb0 = blockIdx.x * SEPB;

  // P1: stage h rows + per-edge min/max (16 threads/edge)
  {
    int et = tid >> 4, sg = tid & 15;
    int e = eb0 + et; if (e >= E) e = E-1;
    uint4 raw = *(const uint4*)((const ushort*)hb + (size_t)e*128 + sg*8);
    *(uint4*)&sH[et][sg*8] = raw;
    uint us[4] = {raw.x, raw.y, raw.z, raw.w};
    float mn = 1e30f, mx = -1e30f;
    #pragma unroll
    for (int i=0;i<4;i++){
      float lo = __uint_as_float(us[i]<<16);
      float hi = __uint_as_float(us[i]&0xFFFF0000u);
      mn = fminf(mn, fminf(lo,hi)); mx = fmaxf(mx, fmaxf(lo,hi));
    }
    #pragma unroll
    for (int o=8;o>0;o>>=1){ mn=fminf(mn,__shfl_xor(mn,o)); mx=fmaxf(mx,__shfl_xor(mx,o)); }
    if (sg==0){ sMin[et]=mn; sMax[et]=mx; }
  }
  __syncthreads();

  // P1b: per-edge A'_q (folded -log2e) + scalars
  for (int t=tid; t<2*SEPB*32; t+=256){
    int et = t>>6, rem = t&63, br = rem>>5, q = rem&31;
    int e = eb0+et; if (e>=E) e=E-1;
    const float* Wa = br ? Wa2 : Wa1;
    float p0=proj[3*e], p1=proj[3*e+1], p2=proj[3*e+2];
    sA[br][et][q] = -(p0*Wa[q]+p1*Wa[32+q]+p2*Wa[64+q])*LOG2E;
  }
  if (tid < SEPB){
    int e = eb0+tid; if (e>=E) e=E-1;
    float range = fmaxf(sMax[tid]-sMin[tid], 1e-3f);
    sH0[tid]=sMin[tid]; sDv[tid]=range*(1.0f/NIV3); sInvD[tid]=(float)NIV3/range;
    sP0[tid]=proj[3*e];
  }
  __syncthreads();

  // P2: value-only node f at 8 nodes (128 tasks = 2 waves; others skip)
  if (tid < SEPB*NND3){
    int et = tid >> 3, nd = tid & 7;
    float hn = fmaf((float)(nd-1), sDv[et], sH0[et]);
    const float* A0 = &sA[0][et][0];
    const float* A1 = &sA[1][et][0];
    float f0 = 0.f, f1 = 0.f;
    #pragma unroll
    for (int q = 0; q < 32; ++q){
      float x0 = fmaf(hn, A0[q], bneg[q]);
      float x1 = fmaf(hn, A1[q], bneg[32+q]);
      float e0 = __builtin_amdgcn_exp2f(x0);
      float e1 = __builtin_amdgcn_exp2f(x1);
      float d0 = 1.0f + e0, d1 = 1.0f + e1;
      float r  = __builtin_amdgcn_rcpf(d0*d1);
      f0 = fmaf(wln[q],    x0*(r*d1), f0);
      f1 = fmaf(wln[32+q], x1*(r*d0), f1);
    }
    sNF[et][0][nd] = f0;
    sNF[et][1][nd] = f1;
  }
  __syncthreads();

  // P2.5: Catmull-Rom coeffs, f32 (5 intervals x 2 br x 16 edges = 160 tasks)
  if (tid < 2*SEPB*NIV3){
    int et = tid/(2*NIV3), rem = tid - et*(2*NIV3), br = rem/NIV3, i = rem - br*NIV3;
    const float* F = &sNF[et][br][0];
    float P0=F[i], P1=F[i+1], P2=F[i+2], P3=F[i+3];
    float bb = br ? bb2v : bb1v;
    f32x4 C;
    C[0] = P1 + bb;
    C[1] = 0.5f*(P2 - P0);
    C[2] = P0 - 2.5f*P1 + 2.0f*P2 - 0.5f*P3;
    C[3] = 0.5f*(P3 - P0) + 1.5f*(P1 - P2);
    sCo[et][br][i] = C;
  }
  __syncthreads();

  // P3: inline eval — 512 tasks (16 edges x 32 groups of 4 channels) -> wpair
  for (int t=tid; t<512; t+=256){
    int et = t>>5, g = t&31;
    int e = eb0 + et;
    if (e < E){
      int d0 = g*4;
      ushort4 hv4 = *(const ushort4*)&sH[et][d0];
      float h0=sH0[et], invD=sInvD[et], p0=sP0[et];
      ushort hvs[4] = {hv4.x, hv4.y, hv4.z, hv4.w};
      uint outp[4];
      #pragma unroll
      for (int k=0;k<4;++k){
        float h = __uint_as_float(((uint)hvs[k])<<16);
        float u = (h - h0) * invD;
        int ii = (int)u; ii = ii < 0 ? 0 : (ii > NIV3-1 ? NIV3-1 : ii);
        float s = u - (float)ii;
        f32x4 CA = sCo[et][0][ii];
        f32x4 CB = sCo[et][1][ii];
        float v1 = fmaf(fmaf(fmaf(CA[3],s,CA[2]),s,CA[1]),s,CA[0]);
        float v2 = fmaf(fmaf(fmaf(CB[3],s,CB[2]),s,CB[1]),s,CB[0]);
        float hp = h * p0;
        outp[k] = packbf2(v1 + hp, v2 + hp);
      }
      uint4 O = {outp[0], outp[1], outp[2], outp[3]};
      *(uint4*)(wp + (size_t)e*128 + d0) = O;
    }
  }
}

// ---------- kernel 4b: per-atom streaming reduce, BOTH layers per block ----------
__global__ __launch_bounds__(128) void reduce_kernel(
    const uint* __restrict__ wpairB,
    const float* __restrict__ ediff, const int* __restrict__ el,
    float* __restrict__ tvec, float* __restrict__ sumwb, int E, int Nl)
{
  __shared__ float sEd[64][3];
  int a = blockIdx.x;
  int d = threadIdx.x;
  const uint* wpL0 = wpairB;
  const uint* wpL1 = wpairB + (size_t)E*128;

  int lo = 0, hi = E;
  while (lo < hi){ int m = (lo+hi)>>1; if (el[m] < a) lo = m+1; else hi = m; }
  int estart = lo;
  int lo2 = lo, hi2 = E;
  while (lo2 < hi2){ int m = (lo2+hi2)>>1; if (el[m] <= a) lo2 = m+1; else hi2 = m; }
  int eend = lo2;

  float s0=0.f, tx0=0.f, ty0=0.f, tz0=0.f;
  float s1=0.f, tx1=0.f, ty1=0.f, tz1=0.f;

  for (int ebase = estart; ebase < eend; ebase += 64){
    int n = min(64, eend - ebase);
    __syncthreads();
    for (int t = d; t < n*3; t += 128)
      ((float*)sEd)[t] = ediff[(size_t)ebase*3 + t];
    __syncthreads();

    #pragma unroll 4
    for (int ei = 0; ei < n; ++ei){
      size_t idx = (size_t)(ebase+ei)*128 + d;
      uint u0v = wpL0[idx];
      uint u1v = wpL1[idx];
      float a1 = __uint_as_float(u0v << 16);
      float b1 = __uint_as_float(u0v & 0xFFFF0000u);
      float a2 = __uint_as_float(u1v << 16);
      float b2 = __uint_as_float(u1v & 0xFFFF0000u);
      float ex = sEd[ei][0], ey = sEd[ei][1], ez = sEd[ei][2];
      s0 += a1;  s1 += a2;
      tx0 = fmaf(ex, b1, tx0);  tx1 = fmaf(ex, b2, tx1);
      ty0 = fmaf(ey, b1, ty0);  ty1 = fmaf(ey, b2, ty1);
      tz0 = fmaf(ez, b1, tz0);  tz1 = fmaf(ez, b2, tz1);
    }
  }

  size_t t0b = (size_t)a*384 + d;
  tvec[t0b      ] = tx0;
  tvec[t0b + 128] = ty0;
  tvec[t0b + 256] = tz0;
  size_t t1b = (size_t)Nl*384 + t0b;
  tvec[t1b      ] = tx1;
  tvec[t1b + 128] = ty1;
  tvec[t1b + 256] = tz1;
  sumwb[(size_t)a*128 + d] = s0;
  sumwb[(size_t)Nl*128 + (size_t)a*128 + d] = s1;
}

// ---------- kernel 5: combine (lv = t0*(1+sumw1)+t1) + head ----------
__global__ __launch_bounds__(128) void head_kernel(
    const float* __restrict__ tvec, const float* __restrict__ sumwb,
    const float* __restrict__ Wl1, const float* __restrict__ bl1,
    const float* __restrict__ Wl2, const float* __restrict__ bl2,
    const float* __restrict__ lvin, float* __restrict__ out, int Nl)
{
  int a = blockIdx.x, d = threadIdx.x;
  __shared__ float slv[3][128];
  __shared__ float sred[2][3];
  const float* t0 = tvec + (size_t)a*384;
  const float* t1 = tvec + (size_t)Nl*384 + (size_t)a*384;
  float m = 1.0f + sumwb[(size_t)Nl*128 + (size_t)a*128 + d];
  slv[0][d] = t0[d      ]*m + t1[d      ];
  slv[1][d] = t0[d + 128]*m + t1[d + 128];
  slv[2][d] = t0[d + 256]*m + t1[d + 256];
  __syncthreads();
  float b = bl1[d];
  float a0 = b, a1 = b, a2 = b;
  #pragma unroll 4
  for (int k = 0; k < 128; ++k) {
    float w = Wl1[k*128 + d];
    a0 = fmaf(slv[0][k], w, a0);
    a1 = fmaf(slv[1][k], w, a1);
    a2 = fmaf(slv[2][k], w, a2);
  }
  float wl2 = Wl2[d];
  float z0 = fmaxf(a0, 0.f)*wl2;
  float z1 = fmaxf(a1, 0.f)*wl2;
  float z2 = fmaxf(a2, 0.f)*wl2;
  #pragma unroll
  for (int off = 32; off > 0; off >>= 1) {
    z0 += __shfl_down(z0, off);
    z1 += __shfl_down(z1, off);
    z2 += __shfl_down(z2, off);
  }
  int wv = d >> 6;
  if ((d & 63) == 0) { sred[wv][0]=z0; sred[wv][1]=z1; sred[wv][2]=z2; }
  __syncthreads();
  if (d == 0) {
    float bb = bl2[0];
    out[a*3+0] = sred[0][0]+sred[1][0] + bb + lvin[a*3+0];
    out[a*3+1] = sred[0][1]+sred[1][1] + bb + lvin[a*3+1];
    out[a*3+2] = sred[0][2]+sred[1][2] + bb + lvin[a*3+2];
  }
}

// ---------- launcher ----------
extern "C" void kernel_launch(void* const* d_in, const int* in_sizes, int n_in,
                              void* d_out, int out_size, void* d_ws, size_t ws_size,
                              hipStream_t stream)
{
  const float* lig   = (const float*)d_in[0];
  const float* lvin  = (const float*)d_in[1];
  const float* posl  = (const float*)d_in[2];
  const float* res   = (const float*)d_in[3];
  const float* posr  = (const float*)d_in[4];
  const int*   el    = (const int*)d_in[7];
  const int*   er    = (const int*)d_in[8];
  const float* Win1  = (const float*)d_in[9];
  const float* bin1  = (const float*)d_in[10];
  const float* Win2  = (const float*)d_in[11];
  const float* bin2  = (const float*)d_in[12];
  const float* Ws1a  = (const float*)d_in[13];
  const float* bs1a  = (const float*)d_in[14];
  const float* Ws1b  = (const float*)d_in[15];
  const float* bs1b  = (const float*)d_in[16];
  const float* Ws2a  = (const float*)d_in[17];
  const float* bs2a  = (const float*)d_in[18];
  const float* Ws2b  = (const float*)d_in[19];
  const float* bs2b  = (const float*)d_in[20];
  const float* Wl1   = (const float*)d_in[21];
  const float* bl1   = (const float*)d_in[22];
  const float* Wl2   = (const float*)d_in[23];
  const float* bl2   = (const float*)d_in[24];

  int Nl = in_sizes[2] / 3;
  int Nr = in_sizes[4] / 3;
  int E  = in_sizes[7];

  char* wsb = (char*)d_ws;
  size_t off = 0;
  auto carve = [&](size_t bytes) -> char* {
    char* p = wsb + off;
    off += (bytes + 255) & ~(size_t)255;
    return p;
  };
  float* ediff  = (float*)carve((size_t)E*3*4);
  float* proj   = (float*)carve((size_t)E*3*4);
  __hip_bfloat16* hbuf2  = (__hip_bfloat16*)carve((size_t)2*E*128*2);
  uint* wpair   = (uint*)carve((size_t)2*E*128*4);
  __hip_bfloat16* ligLb2 = (__hip_bfloat16*)carve((size_t)2*Nl*128*2);
  __hip_bfloat16* resLb2 = (__hip_bfloat16*)carve((size_t)2*Nr*128*2);
  __hip_bfloat16* W1t    = (__hip_bfloat16*)carve((size_t)2*16384*2);
  __hip_bfloat16* W2t    = (__hip_bfloat16*)carve((size_t)2*16384*2);
  float* tvec   = (float*)carve((size_t)2*Nl*384*4);
  float* sumwb  = (float*)carve((size_t)2*Nl*128*4);
  float* bneg   = (float*)carve(128*4);
  float* wln    = (float*)carve(128*4);

  int nBlkLig = (Nl + 63)/64;
  int nBlkRes = (Nr + 63)/64;

  hipLaunchKernelGGL(edgepre_kernel, dim3((E+255)/256), dim3(256), 0, stream,
                     posl, posr, el, er, ediff, proj, E, Nr);
  hipLaunchKernelGGL(prep_kernel, dim3(256), dim3(256), 0, stream,
                     Win1, Win2, W1t, W2t, bs1a, Ws1b, bs2a, Ws2b, bneg, wln);

  hipLaunchKernelGGL(pre_gemm_mfma, dim3(nBlkLig+nBlkRes, 2), dim3(256), 0, stream,
      lig, res, W1t, ligLb2, resLb2, nBlkLig, Nl, Nr);
  hipLaunchKernelGGL(h_gemm2_mfma, dim3((E+63)/64, 2), dim3(256), 0, stream,
      ligLb2, resLb2, el, er, bin1, W2t, bin2, hbuf2, E, Nl, Nr);
  hipLaunchKernelGGL(spline_kernel, dim3((E+SEPB-1)/SEPB, 2), dim3(256), 0, stream,
      hbuf2, proj, Ws1a, Ws2a, bs1b, bs2b, bneg, wln, wpair, E);
  hipLaunchKernelGGL(reduce_kernel, dim3(Nl), dim3(128), 0, stream,
      wpair, ediff, el, tvec, sumwb, E, Nl);
  hipLaunchKernelGGL(head_kernel, dim3(Nl), dim3(128), 0, stream,
      tvec, sumwb, Wl1, bl1, Wl2, bl2, lvin, (float*)d_out, Nl);
}

// Round 19
// 196.068 us; speedup vs baseline: 1.1114x; 1.0298x over previous
//
#include <hip/hip_runtime.h>
#include <hip/hip_bf16.h>
#include <math.h>

typedef short bf16x8 __attribute__((ext_vector_type(8)));
typedef float f32x4 __attribute__((ext_vector_type(4)));

union BU8 { uint4 u; __hip_bfloat16 h[8]; ushort s[8]; };

#define LOG2E 1.44269504f
#define LN2   0.69314718f
#define NIV3  5            // spline intervals
#define NND3  8            // nodes = NIV3 + 3
#define SEPB  32           // edges per spline block (P2 = 256 tasks = 4 full waves)

// ---------- small helpers ----------
__device__ __forceinline__ float3 f3sub(float3 a, float3 b){ return make_float3(a.x-b.x, a.y-b.y, a.z-b.z); }
__device__ __forceinline__ float3 f3nrm(float3 v){
  float n = sqrtf(v.x*v.x + v.y*v.y + v.z*v.z);
  float inv = 1.0f / fmaxf(n, 1e-8f);
  return make_float3(v.x*inv, v.y*inv, v.z*inv);
}
__device__ __forceinline__ float3 f3cross(float3 a, float3 b){
  return make_float3(a.y*b.z - a.z*b.y, a.z*b.x - a.x*b.z, a.x*b.y - a.y*b.x);
}
__device__ __forceinline__ float silu_f(float x){
  float ex = __expf(-x);
  return x * __builtin_amdgcn_rcpf(1.0f + ex);
}
__device__ __forceinline__ uint packbf2(float a, float b){
  ushort ua = __bfloat16_as_ushort(__float2bfloat16(a));
  ushort ub = __bfloat16_as_ushort(__float2bfloat16(b));
  return (uint)ua | ((uint)ub << 16);
}

// ---------- kernel 1: per-edge frame (inline) + diff + proj ----------
__global__ void edgepre_kernel(const float* __restrict__ posl, const float* __restrict__ posr,
    const int* __restrict__ el, const int* __restrict__ er,
    float* __restrict__ ediff, float* __restrict__ proj, int E, int Nr){
  int e = blockIdx.x*blockDim.x + threadIdx.x;
  if (e >= E) return;
  int a = el[e], r = er[e];
  float3 pa = make_float3(posl[3*a+0], posl[3*a+1], posl[3*a+2]);
  float3 pr = make_float3(posr[3*r+0], posr[3*r+1], posr[3*r+2]);
  float3 ed = f3nrm(f3sub(pa,pr));

  int k = r - 1;
  if (k < 0) k = 0;
  int kmax = Nr - 3;
  if (k > kmax) k = kmax;
  float3 p0 = make_float3(posr[3*k+0], posr[3*k+1], posr[3*k+2]);
  float3 p1 = make_float3(posr[3*k+3], posr[3*k+4], posr[3*k+5]);
  float3 p2 = make_float3(posr[3*k+6], posr[3*k+7], posr[3*k+8]);
  float3 u0 = f3nrm(f3sub(p1,p0));
  float3 u1 = f3nrm(f3sub(p2,p1));
  float3 dif = f3nrm(f3sub(u0,u1));
  float3 cr  = f3nrm(f3cross(u0,u1));
  float3 vt  = f3nrm(f3cross(dif,cr));

  float px = ed.x*dif.x + ed.y*cr.x + ed.z*vt.x;
  float py = ed.x*dif.y + ed.y*cr.y + ed.z*vt.y;
  float pz = ed.x*dif.z + ed.y*cr.z + ed.z*vt.z;
  ediff[3*e+0]=ed.x; ediff[3*e+1]=ed.y; ediff[3*e+2]=ed.z;
  proj[3*e+0]=px; proj[3*e+1]=py; proj[3*e+2]=pz;
}

// ---------- kernel P: weight transpose+convert + exp2-folded consts ----------
__global__ void prep_kernel(const float* __restrict__ Win1, const float* __restrict__ Win2,
                            __hip_bfloat16* __restrict__ W1t, __hip_bfloat16* __restrict__ W2t,
                            const float* __restrict__ bs1a, const float* __restrict__ Ws1b,
                            const float* __restrict__ bs2a, const float* __restrict__ Ws2b,
                            float* __restrict__ bneg, float* __restrict__ wln){
  int idx = blockIdx.x*blockDim.x + threadIdx.x;
  if (idx < 32768){
    int l = idx >> 14, rem = idx & 16383, n = rem >> 7, k = rem & 127;
    W1t[idx] = __float2bfloat16(Win1[(l<<14) + (k<<7) + n]);
  } else if (idx < 65536){
    int i2 = idx - 32768;
    int l = i2 >> 14, rem = i2 & 16383, n = rem >> 7, k = rem & 127;
    W2t[i2] = __float2bfloat16(Win2[(l<<14) + (k<<7) + n]);
  }
  if (blockIdx.x == 0 && threadIdx.x < 128){
    int t = threadIdx.x;
    int l = t >> 6, br = (t >> 5) & 1, q = t & 31;
    const float* ba = br ? bs2a : bs1a;
    const float* Wb = br ? Ws2b : Ws1b;
    bneg[t] = -ba[l*32 + q] * LOG2E;
    wln[t]  = -Wb[l*32 + q] * LN2;
  }
}

// ---------- kernel 3a: MFMA pre-GEMM, B in regs, both layers (grid.y = layer) ----------
__global__ __launch_bounds__(256) void pre_gemm_mfma(
    const float* __restrict__ lig, const float* __restrict__ res,
    const __hip_bfloat16* __restrict__ W1t,
    __hip_bfloat16* __restrict__ ligLb, __hip_bfloat16* __restrict__ resLb,
    int nBlkLig, int Nl, int Nr)
{
  __shared__ __hip_bfloat16 sA[64][136];
  int b = blockIdx.x;
  int layer = blockIdx.y;
  const __hip_bfloat16* Wt = W1t + (size_t)layer*16384;
  const float* X; __hip_bfloat16* O; int row0, rows;
  if (b < nBlkLig){ X = lig; O = ligLb + (size_t)layer*Nl*128; row0 = b*64;           rows = Nl; }
  else            { X = res; O = resLb + (size_t)layer*Nr*128; row0 = (b-nBlkLig)*64; rows = Nr; }
  int tid = threadIdx.x;
  int w = tid >> 6, l = tid & 63;
  int lrow = l & 15, lko = (l >> 4) * 8;

  bf16x8 breg[4][2];
  #pragma unroll
  for (int kc4 = 0; kc4 < 4; ++kc4){
    #pragma unroll
    for (int nt = 0; nt < 2; ++nt)
      breg[kc4][nt] = *(const bf16x8*)((const ushort*)Wt + (w*32+nt*16+lrow)*128 + kc4*32 + lko);
  }

  {
    int r = tid >> 2, p = tid & 3, cb = p*32;
    int row = row0 + r; if (row >= rows) row = rows - 1;
    const float* src = X + (size_t)row*128 + cb;
    ushort* dst = (ushort*)&sA[r][0] + cb;
    #pragma unroll
    for (int i = 0; i < 32; i += 8){
      float4 v0 = *(const float4*)(src + i);
      float4 v1 = *(const float4*)(src + i + 4);
      BU8 o;
      o.h[0]=__float2bfloat16(v0.x); o.h[1]=__float2bfloat16(v0.y);
      o.h[2]=__float2bfloat16(v0.z); o.h[3]=__float2bfloat16(v0.w);
      o.h[4]=__float2bfloat16(v1.x); o.h[5]=__float2bfloat16(v1.y);
      o.h[6]=__float2bfloat16(v1.z); o.h[7]=__float2bfloat16(v1.w);
      *(uint4*)(dst + i) = o.u;
    }
  }
  __syncthreads();

  f32x4 acc[4][2];
  for (int mt=0; mt<4; ++mt)
    for (int nt=0; nt<2; ++nt)
      acc[mt][nt] = (f32x4){0.f,0.f,0.f,0.f};

  #pragma unroll
  for (int kc4 = 0; kc4 < 4; ++kc4){
    bf16x8 af[4];
    #pragma unroll
    for (int mt=0; mt<4; ++mt)
      af[mt] = *(const bf16x8*)((const ushort*)&sA[0][0] + (mt*16+lrow)*136 + kc4*32 + lko);
    #pragma unroll
    for (int mt=0; mt<4; ++mt){
      #pragma unroll
      for (int nt=0; nt<2; ++nt)
        acc[mt][nt] = __builtin_amdgcn_mfma_f32_16x16x32_bf16(af[mt], breg[kc4][nt], acc[mt][nt], 0, 0, 0);
    }
  }

  int orow = (l >> 4) * 4;
  #pragma unroll
  for (int mt=0; mt<4; ++mt){
    #pragma unroll
    for (int nt=0; nt<2; ++nt){
      int n = w*32 + nt*16 + (l & 15);
      #pragma unroll
      for (int j=0; j<4; ++j){
        int row = row0 + mt*16 + orow + j;
        if (row < rows) O[(size_t)row*128 + n] = __float2bfloat16(acc[mt][nt][j]);
      }
    }
  }
}

// ---------- kernel 3b: h-GEMM, B in regs, both layers (grid.y = layer) ----------
__global__ __launch_bounds__(256) void h_gemm2_mfma(
    const __hip_bfloat16* __restrict__ ligLbB, const __hip_bfloat16* __restrict__ resLbB,
    const int* __restrict__ el, const int* __restrict__ er,
    const float* __restrict__ b1B, const __hip_bfloat16* __restrict__ W2tB,
    const float* __restrict__ b2B,
    __hip_bfloat16* __restrict__ houtB, int E, int Nl, int Nr)
{
  __shared__ __hip_bfloat16 sA[64][136];
  int tid = threadIdx.x;
  int e0 = blockIdx.x * 64;
  int layer = blockIdx.y;
  const __hip_bfloat16* ligLb = ligLbB + (size_t)layer*Nl*128;
  const __hip_bfloat16* resLb = resLbB + (size_t)layer*Nr*128;
  const float* b1 = b1B + layer*128;
  const __hip_bfloat16* W2t = W2tB + (size_t)layer*16384;
  const float* b2 = b2B + layer*128;
  __hip_bfloat16* hout = houtB + (size_t)layer*E*128;

  int w = tid >> 6, l = tid & 63;
  int lrow = l & 15, lko = (l >> 4) * 8;

  bf16x8 breg[4][2];
  #pragma unroll
  for (int kc4 = 0; kc4 < 4; ++kc4){
    #pragma unroll
    for (int nt = 0; nt < 2; ++nt)
      breg[kc4][nt] = *(const bf16x8*)((const ushort*)W2t + (w*32+nt*16+lrow)*128 + kc4*32 + lko);
  }

  {
    int r = tid >> 2, p = tid & 3, cb = p*32;
    int e = e0 + r; if (e >= E) e = E - 1;
    const ushort* la = (const ushort*)ligLb + (size_t)el[e]*128 + cb;
    const ushort* ra = (const ushort*)resLb + (size_t)er[e]*128 + cb;
    ushort* dst = (ushort*)&sA[r][0] + cb;
    #pragma unroll
    for (int i = 0; i < 32; i += 8){
      BU8 A, B, O;
      A.u = *(const uint4*)(la + i);
      B.u = *(const uint4*)(ra + i);
      float4 bb0 = *(const float4*)(b1 + cb + i);
      float4 bbx = *(const float4*)(b1 + cb + i + 4);
      float bbs[8] = {bb0.x,bb0.y,bb0.z,bb0.w,bbx.x,bbx.y,bbx.z,bbx.w};
      #pragma unroll
      for (int j=0; j<8; ++j){
        float x = __bfloat162float(A.h[j]) + __bfloat162float(B.h[j]) + bbs[j];
        O.h[j] = __float2bfloat16(silu_f(x));
      }
      *(uint4*)(dst + i) = O.u;
    }
  }
  __syncthreads();

  f32x4 acc[4][2];
  for (int mt=0; mt<4; ++mt)
    for (int nt=0; nt<2; ++nt)
      acc[mt][nt] = (f32x4){0.f,0.f,0.f,0.f};

  #pragma unroll
  for (int kc4 = 0; kc4 < 4; ++kc4){
    bf16x8 af[4];
    #pragma unroll
    for (int mt=0; mt<4; ++mt)
      af[mt] = *(const bf16x8*)((const ushort*)&sA[0][0] + (mt*16+lrow)*136 + kc4*32 + lko);
    #pragma unroll
    for (int mt=0; mt<4; ++mt){
      #pragma unroll
      for (int nt=0; nt<2; ++nt)
        acc[mt][nt] = __builtin_amdgcn_mfma_f32_16x16x32_bf16(af[mt], breg[kc4][nt], acc[mt][nt], 0, 0, 0);
    }
  }

  int orow = (l >> 4) * 4;
  #pragma unroll
  for (int mt=0; mt<4; ++mt){
    #pragma unroll
    for (int nt=0; nt<2; ++nt){
      int n = w*32 + nt*16 + (l & 15);
      float bb = b2[n];
      #pragma unroll
      for (int j=0; j<4; ++j){
        int e = e0 + mt*16 + orow + j;
        if (e < E) hout[(size_t)e*128 + n] = __float2bfloat16(acc[mt][nt][j] + bb);
      }
    }
  }
}

// ---------- kernel 4a: per-edge Catmull-Rom spline + inline eval -> wpair ----------
// 32 edges/block, 8 nodes / 5 intervals: node phase = 256 tasks = 4 full waves.
__global__ __launch_bounds__(256) void spline_kernel(
    const __hip_bfloat16* __restrict__ hbufB, const float* __restrict__ proj,
    const float* __restrict__ Ws1a, const float* __restrict__ Ws2a,
    const float* __restrict__ bs1b, const float* __restrict__ bs2b,
    const float* __restrict__ bnegB, const float* __restrict__ wlnB,
    uint* __restrict__ wpairB, int E)
{
  int layer = blockIdx.y;
  const float* Wa1 = Ws1a + layer*96;
  const float* Wa2 = Ws2a + layer*96;
  const float* bneg = bnegB + layer*64;
  const float* wln  = wlnB  + layer*64;
  float bb1v = bs1b[layer], bb2v = bs2b[layer];
  const __hip_bfloat16* hb = hbufB + (size_t)layer*E*128;
  uint* wp = wpairB + (size_t)layer*E*128;

  __shared__ float sA[2][SEPB][36];
  __shared__ float sNF[SEPB][2][NND3];
  __shared__ ushort sH[SEPB][128];
  __shared__ f32x4 sCo[SEPB][2][NIV3];
  __shared__ float sMin[SEPB], sMax[SEPB];
  __shared__ float sH0[SEPB], sDv[SEPB], sInvD[SEPB], sP0[SEPB];

  int tid = threadIdx.x;
  int eb0 = blockIdx.x * SEPB;

  // P1: stage h rows + per-edge min/max (16 threads/edge, two halves)
  #pragma unroll
  for (int half = 0; half < 2; ++half){
    int et = half*16 + (tid >> 4), sg = tid & 15;
    int e = eb0 + et; if (e >= E) e = E-1;
    uint4 raw = *(const uint4*)((const ushort*)hb + (size_t)e*128 + sg*8);
    *(uint4*)&sH[et][sg*8] = raw;
    uint us[4] = {raw.x, raw.y, raw.z, raw.w};
    float mn = 1e30f, mx = -1e30f;
    #pragma unroll
    for (int i=0;i<4;i++){
      float lo = __uint_as_float(us[i]<<16);
      float hi = __uint_as_float(us[i]&0xFFFF0000u);
      mn = fminf(mn, fminf(lo,hi)); mx = fmaxf(mx, fmaxf(lo,hi));
    }
    #pragma unroll
    for (int o=8;o>0;o>>=1){ mn=fminf(mn,__shfl_xor(mn,o)); mx=fmaxf(mx,__shfl_xor(mx,o)); }
    if (sg==0){ sMin[et]=mn; sMax[et]=mx; }
  }
  __syncthreads();

  // P1b: per-edge A'_q (folded -log2e) + scalars (2048 tasks)
  for (int t=tid; t<2*SEPB*32; t+=256){
    int et = t>>6, rem = t&63, br = rem>>5, q = rem&31;
    int e = eb0+et; if (e>=E) e=E-1;
    const float* Wa = br ? Wa2 : Wa1;
    float p0=proj[3*e], p1=proj[3*e+1], p2=proj[3*e+2];
    sA[br][et][q] = -(p0*Wa[q]+p1*Wa[32+q]+p2*Wa[64+q])*LOG2E;
  }
  if (tid < SEPB){
    int e = eb0+tid; if (e>=E) e=E-1;
    float range = fmaxf(sMax[tid]-sMin[tid], 1e-3f);
    sH0[tid]=sMin[tid]; sDv[tid]=range*(1.0f/NIV3); sInvD[tid]=(float)NIV3/range;
    sP0[tid]=proj[3*e];
  }
  __syncthreads();

  // P2: value-only node f at 8 nodes (256 tasks = all 4 waves, no branch)
  {
    int et = tid >> 3, nd = tid & 7;
    float hn = fmaf((float)(nd-1), sDv[et], sH0[et]);
    const float* A0 = &sA[0][et][0];
    const float* A1 = &sA[1][et][0];
    float f0 = 0.f, f1 = 0.f;
    #pragma unroll
    for (int q = 0; q < 32; ++q){
      float x0 = fmaf(hn, A0[q], bneg[q]);
      float x1 = fmaf(hn, A1[q], bneg[32+q]);
      float e0 = __builtin_amdgcn_exp2f(x0);
      float e1 = __builtin_amdgcn_exp2f(x1);
      float d0 = 1.0f + e0, d1 = 1.0f + e1;
      float r  = __builtin_amdgcn_rcpf(d0*d1);
      f0 = fmaf(wln[q],    x0*(r*d1), f0);
      f1 = fmaf(wln[32+q], x1*(r*d0), f1);
    }
    sNF[et][0][nd] = f0;
    sNF[et][1][nd] = f1;
  }
  __syncthreads();

  // P2.5: Catmull-Rom coeffs, f32 (5 intervals x 2 br x 32 edges = 320 tasks)
  for (int t=tid; t<2*SEPB*NIV3; t+=256){
    int et = t/(2*NIV3), rem = t - et*(2*NIV3), br = rem/NIV3, i = rem - br*NIV3;
    const float* F = &sNF[et][br][0];
    float P0=F[i], P1=F[i+1], P2=F[i+2], P3=F[i+3];
    float bb = br ? bb2v : bb1v;
    f32x4 C;
    C[0] = P1 + bb;
    C[1] = 0.5f*(P2 - P0);
    C[2] = P0 - 2.5f*P1 + 2.0f*P2 - 0.5f*P3;
    C[3] = 0.5f*(P3 - P0) + 1.5f*(P1 - P2);
    sCo[et][br][i] = C;
  }
  __syncthreads();

  // P3: inline eval — 1024 tasks (32 edges x 32 groups of 4 channels) -> wpair
  for (int t=tid; t<SEPB*32; t+=256){
    int et = t>>5, g = t&31;
    int e = eb0 + et;
    if (e < E){
      int d0 = g*4;
      ushort4 hv4 = *(const ushort4*)&sH[et][d0];
      float h0=sH0[et], invD=sInvD[et], p0=sP0[et];
      ushort hvs[4] = {hv4.x, hv4.y, hv4.z, hv4.w};
      uint outp[4];
      #pragma unroll
      for (int k=0;k<4;++k){
        float h = __uint_as_float(((uint)hvs[k])<<16);
        float u = (h - h0) * invD;
        int ii = (int)u; ii = ii < 0 ? 0 : (ii > NIV3-1 ? NIV3-1 : ii);
        float s = u - (float)ii;
        f32x4 CA = sCo[et][0][ii];
        f32x4 CB = sCo[et][1][ii];
        float v1 = fmaf(fmaf(fmaf(CA[3],s,CA[2]),s,CA[1]),s,CA[0]);
        float v2 = fmaf(fmaf(fmaf(CB[3],s,CB[2]),s,CB[1]),s,CB[0]);
        float hp = h * p0;
        outp[k] = packbf2(v1 + hp, v2 + hp);
      }
      uint4 O = {outp[0], outp[1], outp[2], outp[3]};
      *(uint4*)(wp + (size_t)e*128 + d0) = O;
    }
  }
}

// ---------- kernel 4b: per-atom streaming reduce, BOTH layers per block ----------
__global__ __launch_bounds__(128) void reduce_kernel(
    const uint* __restrict__ wpairB,
    const float* __restrict__ ediff, const int* __restrict__ el,
    float* __restrict__ tvec, float* __restrict__ sumwb, int E, int Nl)
{
  __shared__ float sEd[64][3];
  int a = blockIdx.x;
  int d = threadIdx.x;
  const uint* wpL0 = wpairB;
  const uint* wpL1 = wpairB + (size_t)E*128;

  int lo = 0, hi = E;
  while (lo < hi){ int m = (lo+hi)>>1; if (el[m] < a) lo = m+1; else hi = m; }
  int estart = lo;
  int lo2 = lo, hi2 = E;
  while (lo2 < hi2){ int m = (lo2+hi2)>>1; if (el[m] <= a) lo2 = m+1; else hi2 = m; }
  int eend = lo2;

  float s0=0.f, tx0=0.f, ty0=0.f, tz0=0.f;
  float s1=0.f, tx1=0.f, ty1=0.f, tz1=0.f;

  for (int ebase = estart; ebase < eend; ebase += 64){
    int n = min(64, eend - ebase);
    __syncthreads();
    for (int t = d; t < n*3; t += 128)
      ((float*)sEd)[t] = ediff[(size_t)ebase*3 + t];
    __syncthreads();

    #pragma unroll 4
    for (int ei = 0; ei < n; ++ei){
      size_t idx = (size_t)(ebase+ei)*128 + d;
      uint u0v = wpL0[idx];
      uint u1v = wpL1[idx];
      float a1 = __uint_as_float(u0v << 16);
      float b1 = __uint_as_float(u0v & 0xFFFF0000u);
      float a2 = __uint_as_float(u1v << 16);
      float b2 = __uint_as_float(u1v & 0xFFFF0000u);
      float ex = sEd[ei][0], ey = sEd[ei][1], ez = sEd[ei][2];
      s0 += a1;  s1 += a2;
      tx0 = fmaf(ex, b1, tx0);  tx1 = fmaf(ex, b2, tx1);
      ty0 = fmaf(ey, b1, ty0);  ty1 = fmaf(ey, b2, ty1);
      tz0 = fmaf(ez, b1, tz0);  tz1 = fmaf(ez, b2, tz1);
    }
  }

  size_t t0b = (size_t)a*384 + d;
  tvec[t0b      ] = tx0;
  tvec[t0b + 128] = ty0;
  tvec[t0b + 256] = tz0;
  size_t t1b = (size_t)Nl*384 + t0b;
  tvec[t1b      ] = tx1;
  tvec[t1b + 128] = ty1;
  tvec[t1b + 256] = tz1;
  sumwb[(size_t)a*128 + d] = s0;
  sumwb[(size_t)Nl*128 + (size_t)a*128 + d] = s1;
}

// ---------- kernel 5: combine (lv = t0*(1+sumw1)+t1) + head ----------
__global__ __launch_bounds__(128) void head_kernel(
    const float* __restrict__ tvec, const float* __restrict__ sumwb,
    const float* __restrict__ Wl1, const float* __restrict__ bl1,
    const float* __restrict__ Wl2, const float* __restrict__ bl2,
    const float* __restrict__ lvin, float* __restrict__ out, int Nl)
{
  int a = blockIdx.x, d = threadIdx.x;
  __shared__ float slv[3][128];
  __shared__ float sred[2][3];
  const float* t0 = tvec + (size_t)a*384;
  const float* t1 = tvec + (size_t)Nl*384 + (size_t)a*384;
  float m = 1.0f + sumwb[(size_t)Nl*128 + (size_t)a*128 + d];
  slv[0][d] = t0[d      ]*m + t1[d      ];
  slv[1][d] = t0[d + 128]*m + t1[d + 128];
  slv[2][d] = t0[d + 256]*m + t1[d + 256];
  __syncthreads();
  float b = bl1[d];
  float a0 = b, a1 = b, a2 = b;
  #pragma unroll 4
  for (int k = 0; k < 128; ++k) {
    float w = Wl1[k*128 + d];
    a0 = fmaf(slv[0][k], w, a0);
    a1 = fmaf(slv[1][k], w, a1);
    a2 = fmaf(slv[2][k], w, a2);
  }
  float wl2 = Wl2[d];
  float z0 = fmaxf(a0, 0.f)*wl2;
  float z1 = fmaxf(a1, 0.f)*wl2;
  float z2 = fmaxf(a2, 0.f)*wl2;
  #pragma unroll
  for (int off = 32; off > 0; off >>= 1) {
    z0 += __shfl_down(z0, off);
    z1 += __shfl_down(z1, off);
    z2 += __shfl_down(z2, off);
  }
  int wv = d >> 6;
  if ((d & 63) == 0) { sred[wv][0]=z0; sred[wv][1]=z1; sred[wv][2]=z2; }
  __syncthreads();
  if (d == 0) {
    float bb = bl2[0];
    out[a*3+0] = sred[0][0]+sred[1][0] + bb + lvin[a*3+0];
    out[a*3+1] = sred[0][1]+sred[1][1] + bb + lvin[a*3+1];
    out[a*3+2] = sred[0][2]+sred[1][2] + bb + lvin[a*3+2];
  }
}

// ---------- launcher ----------
extern "C" void kernel_launch(void* const* d_in, const int* in_sizes, int n_in,
                              void* d_out, int out_size, void* d_ws, size_t ws_size,
                              hipStream_t stream)
{
  const float* lig   = (const float*)d_in[0];
  const float* lvin  = (const float*)d_in[1];
  const float* posl  = (const float*)d_in[2];
  const float* res   = (const float*)d_in[3];
  const float* posr  = (const float*)d_in[4];
  const int*   el    = (const int*)d_in[7];
  const int*   er    = (const int*)d_in[8];
  const float* Win1  = (const float*)d_in[9];
  const float* bin1  = (const float*)d_in[10];
  const float* Win2  = (const float*)d_in[11];
  const float* bin2  = (const float*)d_in[12];
  const float* Ws1a  = (const float*)d_in[13];
  const float* bs1a  = (const float*)d_in[14];
  const float* Ws1b  = (const float*)d_in[15];
  const float* bs1b  = (const float*)d_in[16];
  const float* Ws2a  = (const float*)d_in[17];
  const float* bs2a  = (const float*)d_in[18];
  const float* Ws2b  = (const float*)d_in[19];
  const float* bs2b  = (const float*)d_in[20];
  const float* Wl1   = (const float*)d_in[21];
  const float* bl1   = (const float*)d_in[22];
  const float* Wl2   = (const float*)d_in[23];
  const float* bl2   = (const float*)d_in[24];

  int Nl = in_sizes[2] / 3;
  int Nr = in_sizes[4] / 3;
  int E  = in_sizes[7];

  char* wsb = (char*)d_ws;
  size_t off = 0;
  auto carve = [&](size_t bytes) -> char* {
    char* p = wsb + off;
    off += (bytes + 255) & ~(size_t)255;
    return p;
  };
  float* ediff  = (float*)carve((size_t)E*3*4);
  float* proj   = (float*)carve((size_t)E*3*4);
  __hip_bfloat16* hbuf2  = (__hip_bfloat16*)carve((size_t)2*E*128*2);
  uint* wpair   = (uint*)carve((size_t)2*E*128*4);
  __hip_bfloat16* ligLb2 = (__hip_bfloat16*)carve((size_t)2*Nl*128*2);
  __hip_bfloat16* resLb2 = (__hip_bfloat16*)carve((size_t)2*Nr*128*2);
  __hip_bfloat16* W1t    = (__hip_bfloat16*)carve((size_t)2*16384*2);
  __hip_bfloat16* W2t    = (__hip_bfloat16*)carve((size_t)2*16384*2);
  float* tvec   = (float*)carve((size_t)2*Nl*384*4);
  float* sumwb  = (float*)carve((size_t)2*Nl*128*4);
  float* bneg   = (float*)carve(128*4);
  float* wln    = (float*)carve(128*4);

  int nBlkLig = (Nl + 63)/64;
  int nBlkRes = (Nr + 63)/64;

  hipLaunchKernelGGL(edgepre_kernel, dim3((E+255)/256), dim3(256), 0, stream,
                     posl, posr, el, er, ediff, proj, E, Nr);
  hipLaunchKernelGGL(prep_kernel, dim3(256), dim3(256), 0, stream,
                     Win1, Win2, W1t, W2t, bs1a, Ws1b, bs2a, Ws2b, bneg, wln);

  hipLaunchKernelGGL(pre_gemm_mfma, dim3(nBlkLig+nBlkRes, 2), dim3(256), 0, stream,
      lig, res, W1t, ligLb2, resLb2, nBlkLig, Nl, Nr);
  hipLaunchKernelGGL(h_gemm2_mfma, dim3((E+63)/64, 2), dim3(256), 0, stream,
      ligLb2, resLb2, el, er, bin1, W2t, bin2, hbuf2, E, Nl, Nr);
  hipLaunchKernelGGL(spline_kernel, dim3((E+SEPB-1)/SEPB, 2), dim3(256), 0, stream,
      hbuf2, proj, Ws1a, Ws2a, bs1b, bs2b, bneg, wln, wpair, E);
  hipLaunchKernelGGL(reduce_kernel, dim3(Nl), dim3(128), 0, stream,
      wpair, ediff, el, tvec, sumwb, E, Nl);
  hipLaunchKernelGGL(head_kernel, dim3(Nl), dim3(128), 0, stream,
      tvec, sumwb, Wl1, bl1, Wl2, bl2, lvin, (float*)d_out, Nl);
}